// Round 8
// baseline (607.143 us; speedup 1.0000x reference)
//
#include <hip/hip_runtime.h>

#define N_NODES    100000
#define N_DIH      1000000
#define SCALAR_DIM 128
#define HIDDEN     64
#define ATTR_DIM   3

typedef short v8s __attribute__((ext_vector_type(8)));
typedef float v4f __attribute__((ext_vector_type(4)));
typedef _Float16 v8h __attribute__((ext_vector_type(8)));

__device__ __forceinline__ float silu(float v) {
    return __fdividef(v, 1.0f + __expf(-v));
}

__device__ __forceinline__ unsigned short bf16_rne(float f) {
    unsigned int u = __float_as_uint(f);
    u = (u + 0x7FFFu + ((u >> 16) & 1u)) >> 16;
    return (unsigned short)u;
}

__device__ __forceinline__ float2 bf2_to_f2(unsigned int v) {
    float2 r;
    r.x = __uint_as_float(v << 16);
    r.y = __uint_as_float(v & 0xffff0000u);
    return r;
}

// ---------------- prep ----------------
#define PREP_W   112
#define PREP_W34 33
#define PREP_G   64
#define PREP_H   3907
#define PREP_XB  12500
#define PREP_MAIN (PREP_W + PREP_W34 + PREP_G + PREP_H)
#define PREP_ALL  (PREP_MAIN + PREP_XB)

__global__ void prep_kernel(const float* __restrict__ x, unsigned short* __restrict__ xb,
                            const float* __restrict__ W1, const float* __restrict__ W2,
                            const float* __restrict__ W3, const float* __restrict__ b1,
                            const float* __restrict__ b3,
                            const float* __restrict__ Wout,
                            unsigned short* __restrict__ W1f, unsigned short* __restrict__ W2f,
                            unsigned short* __restrict__ W3f, unsigned short* __restrict__ W1g,
                            float* __restrict__ W34, float* __restrict__ b34,
                            float* __restrict__ PK,
                            const int* __restrict__ qidx,
                            int* __restrict__ cnt_j, int* __restrict__ cnt_k,
                            int* __restrict__ rank_j, int* __restrict__ rank_k) {
    const int b = blockIdx.x;
    if (b < PREP_W) {
        const int tid = b * 256 + threadIdx.x;
        if (tid < 16384) {                     // W1f: kc<8, nt<4
            const int j = tid & 7, lane = (tid >> 3) & 63, t = tid >> 9;
            const int k = (t >> 2) * 32 + ((lane >> 4) << 3) + j;
            const int n = (t & 3) * 16 + (lane & 15);
            W1f[tid] = bf16_rne(W1[k * 64 + n]);
        } else if (tid < 20480) {              // W2f: kc<2, nt<4
            const int i = tid - 16384;
            const int j = i & 7, lane = (i >> 3) & 63, t = i >> 9;
            const int k = (t >> 2) * 32 + ((lane >> 4) << 3) + j;
            const int n = (t & 3) * 16 + (lane & 15);
            W2f[i] = bf16_rne(W2[k * 64 + n]);
        } else if (tid < 28672) {              // W3f (fallback path only)
            const int i = tid - 20480;
            const int j = i & 7, lane = (i >> 3) & 63, t = i >> 9;
            const int k = (t >> 3) * 32 + ((lane >> 4) << 3) + j;
            const int n = (t & 7) * 16 + (lane & 15);
            W3f[i] = bf16_rne(W3[k * 128 + n]);
        }
    } else if (b < PREP_W + PREP_W34) {
        const int t34 = (b - PREP_W) * 256 + threadIdx.x;
        if (t34 < 8192) {                      // W34[r][c] = sum_m W3[r][m]*Wout[m][c]
            const int r = t34 >> 7, c = t34 & 127;
            float s = 0.f;
            #pragma unroll 4
            for (int m = 0; m < 128; ++m) s += W3[r * 128 + m] * Wout[m * 128 + c];
            W34[t34] = s;
        } else if (t34 < 8320) {               // b34[c] = sum_m b3[m]*Wout[m][c]
            const int c = t34 - 8192;
            float s = 0.f;
            #pragma unroll 4
            for (int m = 0; m < 128; ++m) s += b3[m] * Wout[m * 128 + c];
            b34[c] = s;
        } else if (t34 < 8384) {               // PK[c] = {wa0, wa1, wa2, b1}
            const int c = t34 - 8320;
            PK[c * 4 + 0] = W1[256 * 64 + c];
            PK[c * 4 + 1] = W1[257 * 64 + c];
            PK[c * 4 + 2] = W1[258 * 64 + c];
            PK[c * 4 + 3] = b1[c];
        }
    } else if (b < PREP_W + PREP_W34 + PREP_G) {
        // W1g: B-frag pack of W' (128x128), W'[k][n] = n<64 ? W1a[k][n] : W1b[k][n-64]
        const int i = (b - PREP_W - PREP_W34) * 256 + threadIdx.x;   // < 16384
        const int j = i & 7, lane = (i >> 3) & 63, t = i >> 9;       // t < 32
        const int k = (t >> 3) * 32 + ((lane >> 4) << 3) + j;        // k < 128
        const int n = (t & 7) * 16 + (lane & 15);                    // n < 128
        const float w = (n < 64) ? W1[k * 64 + n] : W1[(128 + k) * 64 + (n - 64)];
        W1g[i] = bf16_rne(w);
    } else if (b < PREP_MAIN) {
        const int t = (b - PREP_W - PREP_W34 - PREP_G) * 256 + threadIdx.x;
        if (t < N_DIH) {
            const int rj = atomicAdd(&cnt_j[qidx[N_DIH + t]], 1);
            const int rk = atomicAdd(&cnt_k[qidx[2 * N_DIH + t]], 1);
            if (rank_j != nullptr) {           // uniform branch; fallback passes null
                rank_j[t] = rj;
                rank_k[t] = rk;
            }
        }
    } else {
        const int t = (b - PREP_MAIN) * 256 + threadIdx.x;           // < 3.2M
        const float4 v = *(const float4*)&x[(size_t)t * 4];
        ushort4 o;
        o.x = bf16_rne(v.x); o.y = bf16_rne(v.y); o.z = bf16_rne(v.z); o.w = bf16_rne(v.w);
        *(ushort4*)&xb[(size_t)t * 4] = o;
    }
}

// ---------------- scan: exclusive prefix over counts -> off ----------------
__global__ __launch_bounds__(1024) void scan_kernel(const int* __restrict__ cnt_j,
                                                    const int* __restrict__ cnt_k,
                                                    int* __restrict__ off_j, int* __restrict__ off_k) {
    const int* cnt = blockIdx.x ? cnt_k : cnt_j;
    int* off = blockIdx.x ? off_k : off_j;
    __shared__ int wtot[17];
    const int tid = threadIdx.x, lane = tid & 63, wv = tid >> 6;
    int carry = 0;
    for (int base = 0; base < N_NODES; base += 1024) {
        const int i = base + tid;
        const int v = (i < N_NODES) ? cnt[i] : 0;
        int inc = v;
        #pragma unroll
        for (int o = 1; o < 64; o <<= 1) {
            const int t = __shfl_up(inc, o);
            if (lane >= o) inc += t;
        }
        if (lane == 63) wtot[wv] = inc;
        __syncthreads();
        if (tid == 0) {
            int run = 0;
            #pragma unroll
            for (int w = 0; w < 16; ++w) { const int t = wtot[w]; wtot[w] = run; run += t; }
            wtot[16] = run;
        }
        __syncthreads();
        const int excl = inc - v + wtot[wv] + carry;
        if (i < N_NODES) off[i] = excl;
        carry += wtot[16];
        __syncthreads();
    }
    if (tid == 0) off[N_NODES] = carry;
}

// ---------------- permute: atomic-free scatter using captured ranks ----------------
__global__ void permute_kernel(const int* __restrict__ qidx,
                               const int* __restrict__ off_j, const int* __restrict__ off_k,
                               const int* __restrict__ rank_j, const int* __restrict__ rank_k,
                               int* __restrict__ perm_j, int* __restrict__ perm_k) {
    const int t = blockIdx.x * blockDim.x + threadIdx.x;
    if (t < N_DIH) {
        const int j = qidx[N_DIH + t];
        perm_j[off_j[j] + rank_j[t]] = t;
        const int k = qidx[2 * N_DIH + t];
        perm_k[off_k[k] + rank_k[t]] = t;
    }
}

// ========== uv: per-node partials U = x@W1a, V = x@W1b (f16, row = [U|V]) ==========
#define UVW 3125    // 100000 / 32 rows per wave

__global__ __launch_bounds__(256, 4) void uv_kernel(
    const float* __restrict__ x, const unsigned short* __restrict__ W1g,
    _Float16* __restrict__ uv)
{
    const int tid = threadIdx.x, lane = tid & 63, wv = tid >> 6;
    const int g = blockIdx.x * 4 + wv;
    if (g >= UVW) return;
    const int D0 = g * 32;
    const int m16 = lane & 15, quad = lane >> 4;
    const int r0 = D0 + m16, r1 = D0 + 16 + m16;

    v4f acc[2][8];
    #pragma unroll
    for (int mt = 0; mt < 2; ++mt)
        #pragma unroll
        for (int nt = 0; nt < 8; ++nt) acc[mt][nt] = (v4f){0.f, 0.f, 0.f, 0.f};

    #pragma unroll
    for (int kc = 0; kc < 4; ++kc) {
        const int co = kc * 32 + quad * 8;
        v8s a0, a1;
        {
            const float4 f0 = *(const float4*)&x[(size_t)r0 * 128 + co];
            const float4 f1 = *(const float4*)&x[(size_t)r0 * 128 + co + 4];
            a0[0] = (short)bf16_rne(f0.x); a0[1] = (short)bf16_rne(f0.y);
            a0[2] = (short)bf16_rne(f0.z); a0[3] = (short)bf16_rne(f0.w);
            a0[4] = (short)bf16_rne(f1.x); a0[5] = (short)bf16_rne(f1.y);
            a0[6] = (short)bf16_rne(f1.z); a0[7] = (short)bf16_rne(f1.w);
        }
        {
            const float4 f0 = *(const float4*)&x[(size_t)r1 * 128 + co];
            const float4 f1 = *(const float4*)&x[(size_t)r1 * 128 + co + 4];
            a1[0] = (short)bf16_rne(f0.x); a1[1] = (short)bf16_rne(f0.y);
            a1[2] = (short)bf16_rne(f0.z); a1[3] = (short)bf16_rne(f0.w);
            a1[4] = (short)bf16_rne(f1.x); a1[5] = (short)bf16_rne(f1.y);
            a1[6] = (short)bf16_rne(f1.z); a1[7] = (short)bf16_rne(f1.w);
        }
        #pragma unroll
        for (int nt = 0; nt < 8; ++nt) {
            const v8s bf = *(const v8s*)(W1g + ((kc * 8 + nt) * 64 + lane) * 8);
            acc[0][nt] = __builtin_amdgcn_mfma_f32_16x16x32_bf16(a0, bf, acc[0][nt], 0, 0, 0);
            acc[1][nt] = __builtin_amdgcn_mfma_f32_16x16x32_bf16(a1, bf, acc[1][nt], 0, 0, 0);
        }
    }
    #pragma unroll
    for (int mt = 0; mt < 2; ++mt)
        #pragma unroll
        for (int nt = 0; nt < 8; ++nt) {
            const int c = nt * 16 + m16;
            #pragma unroll
            for (int reg = 0; reg < 4; ++reg) {
                const int n = D0 + mt * 16 + quad * 4 + reg;
                uv[(size_t)n * 128 + c] = (_Float16)acc[mt][nt][reg];
            }
        }
}

#define NW16 62500   // 1e6 / 16 dihedrals per wave

// ========== mlp2s (tier A'): MLP + scatter rows into j-sorted and k-sorted order ==========
__global__ __launch_bounds__(256, 6) void mlp2s_kernel(
    const _Float16* __restrict__ uv, const int* __restrict__ qidx,
    const float* __restrict__ attr, const float* __restrict__ PK,
    const unsigned short* __restrict__ W2f, const float* __restrict__ b2,
    const int* __restrict__ off_j, const int* __restrict__ off_k,
    const int* __restrict__ rank_j, const int* __restrict__ rank_k,
    unsigned short* __restrict__ h2j, unsigned short* __restrict__ h2k)
{
    __shared__ __align__(16) unsigned short hbuf[4][1024];   // per wave: row staging
    const int tid = threadIdx.x, lane = tid & 63, wv = tid >> 6;
    const int g = blockIdx.x * 4 + wv;                       // grid exact: no guard
    const int D0 = g * 16;
    const int m16 = lane & 15, quad = lane >> 4;
    unsigned short* hs = hbuf[wv];

    const int d = D0 + m16;
    const int irow = qidx[d];
    const int lrow = qidx[3 * N_DIH + d];
    const int jn = qidx[N_DIH + d];
    const int kn = qidx[2 * N_DIH + d];
    const int pj = off_j[jn] + rank_j[d];
    const int pk = off_k[kn] + rank_k[d];

    const _Float16* up = uv + (size_t)irow * 128 + quad * 8;       // U part: cols [0,64)
    const _Float16* vp = uv + (size_t)lrow * 128 + 64 + quad * 8;  // V part: cols [64,128)
    const v8h u0 = *(const v8h*)(up + 0);
    const v8h u1 = *(const v8h*)(up + 32);
    const v8h w0 = *(const v8h*)(vp + 0);
    const v8h w1 = *(const v8h*)(vp + 32);
    const float a0 = attr[(size_t)d * 3 + 0];
    const float a1 = attr[(size_t)d * 3 + 1];
    const float a2 = attr[(size_t)d * 3 + 2];

    const int cb = quad * 8;
    v8s af0, af1;
    #pragma unroll
    for (int e = 0; e < 8; ++e) {
        const float4 pk0 = *(const float4*)&PK[(size_t)(cb + e) * 4];
        const float s0 = (float)u0[e] + (float)w0[e] + pk0.x * a0 + pk0.y * a1 + pk0.z * a2 + pk0.w;
        af0[e] = (short)bf16_rne(silu(s0));
        const float4 pk1 = *(const float4*)&PK[(size_t)(32 + cb + e) * 4];
        const float s1 = (float)u1[e] + (float)w1[e] + pk1.x * a0 + pk1.y * a1 + pk1.z * a2 + pk1.w;
        af1[e] = (short)bf16_rne(silu(s1));
    }

    v4f acc2[4];
    #pragma unroll
    for (int nt = 0; nt < 4; ++nt) acc2[nt] = (v4f){0.f, 0.f, 0.f, 0.f};
    #pragma unroll
    for (int nt = 0; nt < 4; ++nt) {
        const v8s bA = *(const v8s*)(W2f + ((nt) * 64 + lane) * 8);
        const v8s bB = *(const v8s*)(W2f + ((4 + nt) * 64 + lane) * 8);
        acc2[nt] = __builtin_amdgcn_mfma_f32_16x16x32_bf16(af0, bA, acc2[nt], 0, 0, 0);
        acc2[nt] = __builtin_amdgcn_mfma_f32_16x16x32_bf16(af1, bB, acc2[nt], 0, 0, 0);
    }

    #pragma unroll
    for (int nt = 0; nt < 4; ++nt) {
        const int c = nt * 16 + m16;
        const float b2c = b2[c];
        #pragma unroll
        for (int reg = 0; reg < 4; ++reg) {
            const int row = quad * 4 + reg;
            hs[row * 64 + c] = bf16_rne(silu(acc2[nt][reg] + b2c));
        }
    }
    const int sub = lane & 7;
    #pragma unroll
    for (int i = 0; i < 2; ++i) {
        const int row = i * 8 + (lane >> 3);
        const int pjr = __shfl(pj, row);
        const int pkr = __shfl(pk, row);
        const v8s rowv = *(const v8s*)(hs + i * 512 + lane * 8);
        *(v8s*)(h2j + (size_t)pjr * 64 + sub * 8) = rowv;
        *(v8s*)(h2k + (size_t)pkr * 64 + sub * 8) = rowv;
    }
}

// ========== mlp2 (tier A): gather f16 uv rows, layer-1 finish, layer-2 MFMA -> h2 ==========
__global__ __launch_bounds__(256, 8) void mlp2_kernel(
    const _Float16* __restrict__ uv, const int* __restrict__ qidx,
    const float* __restrict__ attr, const float* __restrict__ PK,
    const unsigned short* __restrict__ W2f, const float* __restrict__ b2,
    unsigned short* __restrict__ h2)
{
    __shared__ __align__(16) unsigned short hbuf[4][1024];   // per wave: h2 row staging
    const int tid = threadIdx.x, lane = tid & 63, wv = tid >> 6;
    const int g = blockIdx.x * 4 + wv;                       // grid exact: no guard
    const int D0 = g * 16;
    const int m16 = lane & 15, quad = lane >> 4;
    unsigned short* hs = hbuf[wv];

    const int d = D0 + m16;
    const int irow = qidx[d];
    const int lrow = qidx[3 * N_DIH + d];

    const _Float16* up = uv + (size_t)irow * 128 + quad * 8;       // U part: cols [0,64)
    const _Float16* vp = uv + (size_t)lrow * 128 + 64 + quad * 8;  // V part: cols [64,128)
    const v8h u0 = *(const v8h*)(up + 0);
    const v8h u1 = *(const v8h*)(up + 32);
    const v8h w0 = *(const v8h*)(vp + 0);
    const v8h w1 = *(const v8h*)(vp + 32);
    const float a0 = attr[(size_t)d * 3 + 0];
    const float a1 = attr[(size_t)d * 3 + 1];
    const float a2 = attr[(size_t)d * 3 + 2];

    const int cb = quad * 8;
    v8s af0, af1;
    #pragma unroll
    for (int e = 0; e < 8; ++e) {
        const float4 pk0 = *(const float4*)&PK[(size_t)(cb + e) * 4];
        const float s0 = (float)u0[e] + (float)w0[e] + pk0.x * a0 + pk0.y * a1 + pk0.z * a2 + pk0.w;
        af0[e] = (short)bf16_rne(silu(s0));
        const float4 pk1 = *(const float4*)&PK[(size_t)(32 + cb + e) * 4];
        const float s1 = (float)u1[e] + (float)w1[e] + pk1.x * a0 + pk1.y * a1 + pk1.z * a2 + pk1.w;
        af1[e] = (short)bf16_rne(silu(s1));
    }

    v4f acc2[4];
    #pragma unroll
    for (int nt = 0; nt < 4; ++nt) acc2[nt] = (v4f){0.f, 0.f, 0.f, 0.f};
    #pragma unroll
    for (int nt = 0; nt < 4; ++nt) {
        const v8s bA = *(const v8s*)(W2f + ((nt) * 64 + lane) * 8);
        const v8s bB = *(const v8s*)(W2f + ((4 + nt) * 64 + lane) * 8);
        acc2[nt] = __builtin_amdgcn_mfma_f32_16x16x32_bf16(af0, bA, acc2[nt], 0, 0, 0);
        acc2[nt] = __builtin_amdgcn_mfma_f32_16x16x32_bf16(af1, bB, acc2[nt], 0, 0, 0);
    }

    #pragma unroll
    for (int nt = 0; nt < 4; ++nt) {
        const int c = nt * 16 + m16;
        const float b2c = b2[c];
        #pragma unroll
        for (int reg = 0; reg < 4; ++reg) {
            const int row = quad * 4 + reg;
            hs[row * 64 + c] = bf16_rne(silu(acc2[nt][reg] + b2c));
        }
    }
    #pragma unroll
    for (int i = 0; i < 2; ++i) {
        const v8s row16 = *(const v8s*)(hs + i * 512 + lane * 8);
        *(v8s*)(h2 + (size_t)D0 * 64 + i * 512 + lane * 8) = row16;
    }
}

// ========== tier-B MLP (kept verbatim for smaller workspaces) ==========
#define NWAVES 31250    // 1e6 / 32

__global__ __launch_bounds__(256, 8) void mlp12_kernel(
    const unsigned short* __restrict__ xb, const int* __restrict__ qidx,
    const float* __restrict__ attr,
    const float* __restrict__ W1, const float* __restrict__ b1,
    const float* __restrict__ b2,
    const unsigned short* __restrict__ W1f, const unsigned short* __restrict__ W2f,
    unsigned short* __restrict__ h2)
{
    __shared__ __align__(16) unsigned short hbuf[4][1024];
    const int tid  = threadIdx.x;
    const int lane = tid & 63;
    const int wv   = tid >> 6;
    const int g    = blockIdx.x * 4 + wv;
    const int D0   = g * 16;
    const int m16  = lane & 15;
    const int quad = lane >> 4;
    unsigned short* hs = hbuf[wv];

    const int irow = qidx[D0 + m16];
    const int lrow = qidx[3 * N_DIH + D0 + m16];

    v4f acc[4];
    #pragma unroll
    for (int nt = 0; nt < 4; ++nt) acc[nt] = (v4f){0.f, 0.f, 0.f, 0.f};

    #pragma unroll
    for (int kc = 0; kc < 8; ++kc) {
        const int side = kc >> 2;
        const int coff = (kc & 3) * 32 + quad * 8;
        const int r0 = side ? lrow : irow;
        const v8s a0 = *(const v8s*)(xb + (size_t)r0 * 128 + coff);
        #pragma unroll
        for (int nt = 0; nt < 4; ++nt) {
            const v8s b = *(const v8s*)(W1f + ((kc * 4 + nt) * 64 + lane) * 8);
            acc[nt] = __builtin_amdgcn_mfma_f32_16x16x32_bf16(a0, b, acc[nt], 0, 0, 0);
        }
    }

    #pragma unroll
    for (int nt = 0; nt < 4; ++nt) {
        const int c = nt * 16 + m16;
        const float b1c = b1[c];
        const float wa0 = W1[256 * 64 + c];
        const float wa1 = W1[257 * 64 + c];
        const float wa2 = W1[258 * 64 + c];
        const int quadp = (nt * 2 + (m16 >> 3)) & 3;
        const int jp    = m16 & 7;
        const int kc2   = nt >> 1;
        #pragma unroll
        for (int reg = 0; reg < 4; ++reg) {
            const int r = quad * 4 + reg;
            const int d = D0 + r;
            float v = acc[nt][reg] + b1c
                    + attr[(size_t)d * 3 + 0] * wa0
                    + attr[(size_t)d * 3 + 1] * wa1
                    + attr[(size_t)d * 3 + 2] * wa2;
            v = silu(v);
            hs[kc2 * 512 + (r + 16 * quadp) * 8 + jp] = bf16_rne(v);
        }
    }

    v4f acc2[4];
    #pragma unroll
    for (int nt = 0; nt < 4; ++nt) acc2[nt] = (v4f){0.f, 0.f, 0.f, 0.f};

    #pragma unroll
    for (int kc = 0; kc < 2; ++kc) {
        const v8s a0 = *(const v8s*)(hs + kc * 512 + lane * 8);
        #pragma unroll
        for (int nt = 0; nt < 4; ++nt) {
            const v8s b = *(const v8s*)(W2f + ((kc * 4 + nt) * 64 + lane) * 8);
            acc2[nt] = __builtin_amdgcn_mfma_f32_16x16x32_bf16(a0, b, acc2[nt], 0, 0, 0);
        }
    }

    #pragma unroll
    for (int nt = 0; nt < 4; ++nt) {
        const int c = nt * 16 + m16;
        const float b2c = b2[c];
        #pragma unroll
        for (int reg = 0; reg < 4; ++reg) {
            const int row = quad * 4 + reg;
            hs[row * 64 + c] = bf16_rne(silu(acc2[nt][reg] + b2c));
        }
    }
    #pragma unroll
    for (int i = 0; i < 2; ++i) {
        const v8s row16 = *(const v8s*)(hs + i * 512 + lane * 8);
        *(v8s*)(h2 + (size_t)D0 * 64 + i * 512 + lane * 8) = row16;
    }
}

// ====== aggregate (tier A'): STREAMING reads of pre-sorted h2j/h2k + fused W34 GEMM ======
__global__ __launch_bounds__(256, 2) void aggregate_seq(
    const unsigned short* __restrict__ h2j, const unsigned short* __restrict__ h2k,
    const int* __restrict__ off_j, const int* __restrict__ off_k,
    const float* __restrict__ W34, const float* __restrict__ b34,
    float* __restrict__ out)
{
    __shared__ float a_lds[64 * 132];
    const int tid    = threadIdx.x;
    const int lane   = tid & 63;
    const int wv     = __builtin_amdgcn_readfirstlane(tid >> 6);
    const int base   = blockIdx.x * 64;
    const int half   = lane >> 5;
    const int lane31 = lane & 31;

    for (int p = 0; p < 16; ++p) {
        const int ln = wv * 16 + p;
        const int n  = base + ln;
        float sx = 0.f, sy = 0.f, bf = 0.f;
        if (n < N_NODES) {
            int cj, ck;
            {
                const int e0 = off_j[n], e1 = off_j[n + 1];
                cj = e1 - e0;
                float ax = 0.f, ay = 0.f;
                int e = e0;
                for (; e + 4 <= e1; e += 4) {
                    const float2 fA = bf2_to_f2(*(const unsigned int*)(h2j + (size_t)(e + half) * 64 + lane31 * 2));
                    const float2 fB = bf2_to_f2(*(const unsigned int*)(h2j + (size_t)(e + 2 + half) * 64 + lane31 * 2));
                    ax += fA.x + fB.x; ay += fA.y + fB.y;
                }
                if (e + 2 <= e1) {
                    const float2 f = bf2_to_f2(*(const unsigned int*)(h2j + (size_t)(e + half) * 64 + lane31 * 2));
                    ax += f.x; ay += f.y;
                    e += 2;
                }
                if (e < e1 && half == 0) {
                    const float2 f = bf2_to_f2(*(const unsigned int*)(h2j + (size_t)e * 64 + lane31 * 2));
                    ax += f.x; ay += f.y;
                }
                ax += __shfl_xor(ax, 32);
                ay += __shfl_xor(ay, 32);
                const float inv = 1.0f / (float)max(cj, 1);
                sx += ax * inv; sy += ay * inv;
            }
            {
                const int e0 = off_k[n], e1 = off_k[n + 1];
                ck = e1 - e0;
                float ax = 0.f, ay = 0.f;
                int e = e0;
                for (; e + 4 <= e1; e += 4) {
                    const float2 fA = bf2_to_f2(*(const unsigned int*)(h2k + (size_t)(e + half) * 64 + lane31 * 2));
                    const float2 fB = bf2_to_f2(*(const unsigned int*)(h2k + (size_t)(e + 2 + half) * 64 + lane31 * 2));
                    ax += fA.x + fB.x; ay += fA.y + fB.y;
                }
                if (e + 2 <= e1) {
                    const float2 f = bf2_to_f2(*(const unsigned int*)(h2k + (size_t)(e + half) * 64 + lane31 * 2));
                    ax += f.x; ay += f.y;
                    e += 2;
                }
                if (e < e1 && half == 0) {
                    const float2 f = bf2_to_f2(*(const unsigned int*)(h2k + (size_t)e * 64 + lane31 * 2));
                    ax += f.x; ay += f.y;
                }
                ax += __shfl_xor(ax, 32);
                ay += __shfl_xor(ay, 32);
                const float inv = 1.0f / (float)max(ck, 1);
                sx += ax * inv; sy += ay * inv;
            }
            bf = 0.5f * ((float)(cj > 0) + (float)(ck > 0));
        }
        if (half == 0) {
            float2 w; w.x = sx * 0.5f; w.y = sy * 0.5f;
            *(float2*)&a_lds[ln * 132 + 2 * lane31] = w;
            if (lane31 == 0) a_lds[ln * 132 + 128] = bf;
        }
    }
    __syncthreads();

    const int co = wv * 32;
    const float bfv = a_lds[lane * 132 + 128];
    float acc[32];
    #pragma unroll
    for (int c = 0; c < 32; ++c) acc[c] = bfv * b34[co + c];
    const float* ap = &a_lds[lane * 132];
    #pragma unroll 2
    for (int d = 0; d < 64; d += 4) {
        const float4 av = *(const float4*)&ap[d];
        const float* w0 = &W34[(d + 0) * 128 + co];
        const float* w1 = w0 + 128;
        const float* w2 = w0 + 256;
        const float* w3 = w0 + 384;
        #pragma unroll
        for (int c = 0; c < 32; ++c)
            acc[c] += av.x * w0[c] + av.y * w1[c] + av.z * w2[c] + av.w * w3[c];
    }
    __syncthreads();
    #pragma unroll
    for (int c = 0; c < 32; c += 4)
        *(float4*)&a_lds[lane * 132 + co + c] = make_float4(acc[c], acc[c+1], acc[c+2], acc[c+3]);
    __syncthreads();
    const int q4 = lane31 << 2;
    #pragma unroll
    for (int p = 0; p < 8; ++p) {
        const int ln = wv * 16 + p * 2 + half;
        const int n  = base + ln;
        if (n < N_NODES)
            *(float4*)&out[(size_t)n * 128 + q4] = *(const float4*)&a_lds[ln * 132 + q4];
    }
}

// ====== aggregate (tier A/B): 32-node tile, perm-prefetch, 8 blocks/CU ======
// R8: (1) lane-cooperative perm prefetch (one coalesced 32-entry load per list
// chunk; row addresses via register __shfl) removes the L2 round trip that
// serialized each 8-row batch; (2) 32-node tile halves LDS -> 8 blocks/CU.
#define ATILE 32
__global__ __launch_bounds__(256, 8) void aggregate_out64(
    const unsigned short* __restrict__ h2,
    const int* __restrict__ off_j, const int* __restrict__ off_k,
    const int* __restrict__ perm_j, const int* __restrict__ perm_k,
    const float* __restrict__ W34, const float* __restrict__ b34,
    float* __restrict__ out)
{
    __shared__ float a_lds[ATILE * 132];   // [node][0..63]=aggH, [128]=bias flag (16.9 KB)
    const int tid    = threadIdx.x;
    const int lane   = tid & 63;
    const int wv     = __builtin_amdgcn_readfirstlane(tid >> 6);  // 0..3
    const int base   = blockIdx.x * ATILE;
    const int half   = lane >> 5;
    const int lane31 = lane & 31;

    // phase 1: 8 half-waves x 4 nodes each; half-wave owns the full 128B row
    for (int p = 0; p < 4; ++p) {
        const int ln = wv * 8 + p * 2 + half;
        const int n  = base + ln;
        float sx = 0.f, sy = 0.f, bf = 0.f;
        if (n < N_NODES) {
            int cnt2[2];
            #pragma unroll
            for (int li = 0; li < 2; ++li) {
                const int* offp  = li ? off_k  : off_j;
                const int* permp = li ? perm_k : perm_j;
                const int e0 = offp[n], e1 = offp[n + 1];
                cnt2[li] = e1 - e0;
                float ax = 0.f, ay = 0.f;
                for (int eb = e0; eb < e1; eb += 32) {
                    const int m = min(e1 - eb, 32);
                    int dv = 0;
                    if (lane31 < m) dv = permp[eb + lane31];   // one coalesced load
                    int q = 0;
                    for (; q + 8 <= m; q += 8) {
                        unsigned int rr[8];
                        #pragma unroll
                        for (int t = 0; t < 8; ++t) {
                            const int dq = __shfl(dv, q + t, 32);   // register, no mem
                            rr[t] = *(const unsigned int*)(h2 + (size_t)dq * 64 + lane31 * 2);
                        }
                        #pragma unroll
                        for (int t = 0; t < 8; ++t) {
                            const float2 f = bf2_to_f2(rr[t]);
                            ax += f.x; ay += f.y;
                        }
                    }
                    for (; q < m; ++q) {
                        const int dq = __shfl(dv, q, 32);
                        const float2 f = bf2_to_f2(*(const unsigned int*)(h2 + (size_t)dq * 64 + lane31 * 2));
                        ax += f.x; ay += f.y;
                    }
                }
                const float inv = 1.0f / (float)max(cnt2[li], 1);
                sx += ax * inv; sy += ay * inv;
            }
            bf = 0.5f * ((float)(cnt2[0] > 0) + (float)(cnt2[1] > 0));
        }
        float2 w; w.x = sx * 0.5f; w.y = sy * 0.5f;
        *(float2*)&a_lds[ln * 132 + 2 * lane31] = w;
        if (lane31 == 0) a_lds[ln * 132 + 128] = bf;
    }
    __syncthreads();

    // phase 2: thread = (node=lane31, 16-col group co=(wv*2+half)*16)
    const int node = lane31;
    const int co = (wv * 2 + half) * 16;
    const float bfv = a_lds[node * 132 + 128];
    float acc[16];
    #pragma unroll
    for (int c = 0; c < 16; ++c) acc[c] = bfv * b34[co + c];
    const float* ap = &a_lds[node * 132];
    #pragma unroll 2
    for (int d = 0; d < 64; d += 4) {
        const float4 av = *(const float4*)&ap[d];
        const float* w0 = &W34[(d + 0) * 128 + co];
        const float* w1 = w0 + 128;
        const float* w2 = w0 + 256;
        const float* w3 = w0 + 384;
        #pragma unroll
        for (int c = 0; c < 16; ++c)
            acc[c] += av.x * w0[c] + av.y * w1[c] + av.z * w2[c] + av.w * w3[c];
    }
    __syncthreads();
    #pragma unroll
    for (int c = 0; c < 16; c += 4)
        *(float4*)&a_lds[node * 132 + co + c] = make_float4(acc[c], acc[c+1], acc[c+2], acc[c+3]);
    __syncthreads();
    const int q4 = lane31 << 2;    // each half stores one full 512B node row
    #pragma unroll
    for (int p = 0; p < 4; ++p) {
        const int ln = wv * 8 + p * 2 + half;
        const int n  = base + ln;
        if (n < N_NODES)
            *(float4*)&out[(size_t)n * 128 + q4] = *(const float4*)&a_lds[ln * 132 + q4];
    }
}

// ================= fallback (proven R3 atomic path) =================
__global__ void scale_kernel(const int* __restrict__ cnt_j, const int* __restrict__ cnt_k,
                             float* __restrict__ scale_j, float* __restrict__ scale_k) {
    int n = blockIdx.x * blockDim.x + threadIdx.x;
    if (n < N_NODES) {
        scale_j[n] = 0.5f / (float)max(cnt_j[n], 1);
        scale_k[n] = 0.5f / (float)max(cnt_k[n], 1);
    }
}

__global__ __launch_bounds__(256, 3) void mlp_mfma_atomic(
    const unsigned short* __restrict__ xb, const int* __restrict__ qidx,
    const float* __restrict__ attr,
    const float* __restrict__ W1, const float* __restrict__ b1,
    const float* __restrict__ b2, const float* __restrict__ b3,
    const unsigned short* __restrict__ W1f, const unsigned short* __restrict__ W2f,
    const unsigned short* __restrict__ W3f,
    const float* __restrict__ scale_j, const float* __restrict__ scale_k,
    float* __restrict__ aggr)
{
    __shared__ __align__(16) unsigned short hbuf[4][4096];
    const int tid  = threadIdx.x;
    const int lane = tid & 63;
    const int wv   = tid >> 6;
    const int g    = blockIdx.x * 4 + wv;
    if (g >= NWAVES) return;
    const int D0   = g * 32;
    const int m16  = lane & 15;
    const int quad = lane >> 4;
    unsigned short* hs = hbuf[wv];

    int irow[2], lrow[2];
    irow[0] = qidx[D0 + m16];
    irow[1] = qidx[D0 + 16 + m16];
    lrow[0] = qidx[3 * N_DIH + D0 + m16];
    lrow[1] = qidx[3 * N_DIH + D0 + 16 + m16];

    v4f acc[2][4];
    #pragma unroll
    for (int mt = 0; mt < 2; ++mt)
        #pragma unroll
        for (int nt = 0; nt < 4; ++nt) acc[mt][nt] = (v4f){0.f, 0.f, 0.f, 0.f};
    #pragma unroll
    for (int kc = 0; kc < 8; ++kc) {
        const int side = kc >> 2;
        const int coff = (kc & 3) * 32 + quad * 8;
        const int r0 = side ? lrow[0] : irow[0];
        const int r1 = side ? lrow[1] : irow[1];
        const v8s a0 = *(const v8s*)(xb + (size_t)r0 * 128 + coff);
        const v8s a1 = *(const v8s*)(xb + (size_t)r1 * 128 + coff);
        #pragma unroll
        for (int nt = 0; nt < 4; ++nt) {
            const v8s b = *(const v8s*)(W1f + ((kc * 4 + nt) * 64 + lane) * 8);
            acc[0][nt] = __builtin_amdgcn_mfma_f32_16x16x32_bf16(a0, b, acc[0][nt], 0, 0, 0);
            acc[1][nt] = __builtin_amdgcn_mfma_f32_16x16x32_bf16(a1, b, acc[1][nt], 0, 0, 0);
        }
    }
    #pragma unroll
    for (int mt = 0; mt < 2; ++mt) {
        #pragma unroll
        for (int nt = 0; nt < 4; ++nt) {
            const int c = nt * 16 + m16;
            const float b1c = b1[c];
            const float wa0 = W1[256 * 64 + c];
            const float wa1 = W1[257 * 64 + c];
            const float wa2 = W1[258 * 64 + c];
            const int quadp = (nt * 2 + (m16 >> 3)) & 3;
            const int jp    = m16 & 7;
            const int kc2   = nt >> 1;
            #pragma unroll
            for (int reg = 0; reg < 4; ++reg) {
                const int r = quad * 4 + reg;
                const int d = D0 + mt * 16 + r;
                float v = acc[mt][nt][reg] + b1c
                        + attr[(size_t)d * 3 + 0] * wa0
                        + attr[(size_t)d * 3 + 1] * wa1
                        + attr[(size_t)d * 3 + 2] * wa2;
                v = silu(v);
                hs[mt * 1024 + kc2 * 512 + (r + 16 * quadp) * 8 + jp] = bf16_rne(v);
            }
        }
    }
    v4f acc2[2][4];
    #pragma unroll
    for (int mt = 0; mt < 2; ++mt)
        #pragma unroll
        for (int nt = 0; nt < 4; ++nt) acc2[mt][nt] = (v4f){0.f, 0.f, 0.f, 0.f};
    #pragma unroll
    for (int kc = 0; kc < 2; ++kc) {
        const v8s a0 = *(const v8s*)(hs +        kc * 512 + lane * 8);
        const v8s a1 = *(const v8s*)(hs + 1024 + kc * 512 + lane * 8);
        #pragma unroll
        for (int nt = 0; nt < 4; ++nt) {
            const v8s b = *(const v8s*)(W2f + ((kc * 4 + nt) * 64 + lane) * 8);
            acc2[0][nt] = __builtin_amdgcn_mfma_f32_16x16x32_bf16(a0, b, acc2[0][nt], 0, 0, 0);
            acc2[1][nt] = __builtin_amdgcn_mfma_f32_16x16x32_bf16(a1, b, acc2[1][nt], 0, 0, 0);
        }
    }
    #pragma unroll
    for (int mt = 0; mt < 2; ++mt) {
        #pragma unroll
        for (int nt = 0; nt < 4; ++nt) {
            const float b2c = b2[nt * 16 + m16];
            const int quadp = (nt * 2 + (m16 >> 3)) & 3;
            const int jp    = m16 & 7;
            const int kc2   = nt >> 1;
            #pragma unroll
            for (int reg = 0; reg < 4; ++reg) {
                const int r = quad * 4 + reg;
                const float v = silu(acc2[mt][nt][reg] + b2c);
                hs[2048 + mt * 1024 + kc2 * 512 + (r + 16 * quadp) * 8 + jp] = bf16_rne(v);
            }
        }
    }
    v4f acc3[2][8];
    #pragma unroll
    for (int mt = 0; mt < 2; ++mt)
        #pragma unroll
        for (int nt = 0; nt < 8; ++nt) acc3[mt][nt] = (v4f){0.f, 0.f, 0.f, 0.f};
    #pragma unroll
    for (int kc = 0; kc < 2; ++kc) {
        const v8s a0 = *(const v8s*)(hs + 2048 +        kc * 512 + lane * 8);
        const v8s a1 = *(const v8s*)(hs + 2048 + 1024 + kc * 512 + lane * 8);
        #pragma unroll
        for (int nt = 0; nt < 8; ++nt) {
            const v8s b = *(const v8s*)(W3f + ((kc * 8 + nt) * 64 + lane) * 8);
            acc3[0][nt] = __builtin_amdgcn_mfma_f32_16x16x32_bf16(a0, b, acc3[0][nt], 0, 0, 0);
            acc3[1][nt] = __builtin_amdgcn_mfma_f32_16x16x32_bf16(a1, b, acc3[1][nt], 0, 0, 0);
        }
    }
    #pragma unroll
    for (int mt = 0; mt < 2; ++mt) {
        int jn[4], kn[4]; float sjv[4], skv[4];
        #pragma unroll
        for (int reg = 0; reg < 4; ++reg) {
            const int d = D0 + mt * 16 + quad * 4 + reg;
            jn[reg] = qidx[N_DIH + d];
            kn[reg] = qidx[2 * N_DIH + d];
            sjv[reg] = scale_j[jn[reg]];
            skv[reg] = scale_k[kn[reg]];
        }
        #pragma unroll
        for (int nt = 0; nt < 8; ++nt) {
            const int c = nt * 16 + m16;
            const float b3c = b3[c];
            #pragma unroll
            for (int reg = 0; reg < 4; ++reg) {
                const float v = acc3[mt][nt][reg] + b3c;
                atomicAdd(&aggr[(size_t)jn[reg] * 128 + c], v * sjv[reg]);
                atomicAdd(&aggr[(size_t)kn[reg] * 128 + c], v * skv[reg]);
            }
        }
    }
}

#define OB    256
#define OTILE 64
__global__ __launch_bounds__(OB, 2) void out_kernel(const float* __restrict__ aggr,
                                                    const float* __restrict__ Wout,
                                                    float* __restrict__ out) {
    __shared__ float a_lds[OTILE * 132];
    const int tid  = threadIdx.x;
    const int lane = tid & 63;
    const int wv   = __builtin_amdgcn_readfirstlane(tid >> 6);
    const int base = blockIdx.x * OTILE;
    const int half = lane >> 5;
    const int q4   = (lane & 31) << 2;
    #pragma unroll
    for (int p = 0; p < 8; ++p) {
        const int ln = wv * 16 + p * 2 + half;
        const int n  = base + ln;
        float4 v = make_float4(0.f, 0.f, 0.f, 0.f);
        if (n < N_NODES) v = *(const float4*)&aggr[(size_t)n * 128 + q4];
        *(float4*)&a_lds[ln * 132 + q4] = v;
    }
    __syncthreads();
    const int c0 = wv * 32;
    float acc[32];
    #pragma unroll
    for (int c = 0; c < 32; ++c) acc[c] = 0.0f;
    const float* ap = &a_lds[lane * 132];
    #pragma unroll 2
    for (int d = 0; d < 128; d += 4) {
        const float4 av = *(const float4*)&ap[d];
        const float* w0 = &Wout[(d + 0) * 128 + c0];
        const float* w1 = &Wout[(d + 1) * 128 + c0];
        const float* w2 = &Wout[(d + 2) * 128 + c0];
        const float* w3 = &Wout[(d + 3) * 128 + c0];
        #pragma unroll
        for (int c = 0; c < 32; ++c)
            acc[c] += av.x * w0[c] + av.y * w1[c] + av.z * w2[c] + av.w * w3[c];
    }
    __syncthreads();
    #pragma unroll
    for (int c = 0; c < 32; c += 4)
        *(float4*)&a_lds[lane * 132 + c0 + c] = make_float4(acc[c], acc[c+1], acc[c+2], acc[c+3]);
    __syncthreads();
    #pragma unroll
    for (int p = 0; p < 8; ++p) {
        const int ln = wv * 16 + p * 2 + half;
        const int n  = base + ln;
        if (n < N_NODES)
            *(float4*)&out[(size_t)n * 128 + q4] = *(const float4*)&a_lds[ln * 132 + q4];
    }
}

extern "C" void kernel_launch(void* const* d_in, const int* in_sizes, int n_in,
                              void* d_out, int out_size, void* d_ws, size_t ws_size,
                              hipStream_t stream) {
    const float* x    = (const float*)d_in[0];
    const int*   qidx = (const int*)d_in[1];
    const float* attr = (const float*)d_in[2];
    const float* W1   = (const float*)d_in[3];
    const float* b1   = (const float*)d_in[4];
    const float* W2   = (const float*)d_in[5];
    const float* b2   = (const float*)d_in[6];
    const float* W3   = (const float*)d_in[7];
    const float* b3   = (const float*)d_in[8];
    const float* Wout = (const float*)d_in[9];
    float* out = (float*)d_out;
    float* wsf = (float*)d_ws;

    const size_t words = ws_size / 4;
    if (words >= (size_t)79300000) {
        // ---- tier A': scatter-on-write path (316.9 MB; inert on smaller ws) ----
        size_t o = 0;
        unsigned short* h2j = (unsigned short*)wsf;          o += 32000000;
        unsigned short* h2k = (unsigned short*)(wsf + o);    o += 32000000;
        _Float16* uvp = (_Float16*)(wsf + o);                o += 12800000;  // f16: half used
        unsigned short* W1f = (unsigned short*)(wsf + o);    o += 8192;
        unsigned short* W2f = (unsigned short*)(wsf + o);    o += 2048;
        unsigned short* W3f = (unsigned short*)(wsf + o);    o += 4096;
        unsigned short* W1g = (unsigned short*)(wsf + o);    o += 8192;
        float* W34  = wsf + o;                               o += 8192;
        float* b34  = wsf + o;                               o += 128;
        float* PK   = wsf + o;                               o += 256;
        int* cnt_j  = (int*)(wsf + o);                       o += 100000;
        int* cnt_k  = (int*)(wsf + o);                       o += 100000;
        int* off_j  = (int*)(wsf + o);                       o += 100001;
        int* off_k  = (int*)(wsf + o);                       o += 100001;
        int* rank_j = (int*)(wsf + o);                       o += 1000000;
        int* rank_k = (int*)(wsf + o);                       o += 1000000;

        hipMemsetAsync(cnt_j, 0, (size_t)200000 * sizeof(int), stream);
        prep_kernel<<<PREP_MAIN, 256, 0, stream>>>(
            x, h2j /*xb unused*/, W1, W2, W3, b1, b3, Wout,
            W1f, W2f, W3f, W1g, W34, b34, PK, qidx, cnt_j, cnt_k, rank_j, rank_k);
        scan_kernel<<<2, 1024, 0, stream>>>(cnt_j, cnt_k, off_j, off_k);
        uv_kernel<<<(UVW + 3) / 4, 256, 0, stream>>>(x, W1g, uvp);
        mlp2s_kernel<<<NW16 / 4, 256, 0, stream>>>(
            uvp, qidx, attr, PK, W2f, b2, off_j, off_k, rank_j, rank_k, h2j, h2k);
        aggregate_seq<<<(N_NODES + 63) / 64, 256, 0, stream>>>(
            h2j, h2k, off_j, off_k, W34, b34, out);
    } else if (words >= (size_t)47500000) {
        // ---- tier A: uv-precompute + perm-gather path (ACTIVE on this ws) ----
        size_t o = 0;
        unsigned short* h2  = (unsigned short*)wsf;          o += 32000000;
        _Float16* uvp = (_Float16*)(wsf + o);                o += 12800000;  // f16: half used
        unsigned short* W1f = (unsigned short*)(wsf + o);    o += 8192;
        unsigned short* W2f = (unsigned short*)(wsf + o);    o += 2048;
        unsigned short* W3f = (unsigned short*)(wsf + o);    o += 4096;
        unsigned short* W1g = (unsigned short*)(wsf + o);    o += 8192;
        float* W34  = wsf + o;                               o += 8192;
        float* b34  = wsf + o;                               o += 128;
        float* PK   = wsf + o;                               o += 256;
        int* cnt_j  = (int*)(wsf + o);                       o += 100000;
        int* cnt_k  = (int*)(wsf + o);                       o += 100000;
        int* off_j  = (int*)(wsf + o);                       o += 100001;
        int* off_k  = (int*)(wsf + o);                       o += 100001;
        int* perm_j = (int*)(wsf + o);                       o += 1000000;
        int* perm_k = (int*)(wsf + o);                       o += 1000000;
        int* rank_j = (int*)h2;
        int* rank_k = rank_j + N_DIH;

        hipMemsetAsync(cnt_j, 0, (size_t)200000 * sizeof(int), stream);
        prep_kernel<<<PREP_MAIN, 256, 0, stream>>>(
            x, h2 /*xb unused*/, W1, W2, W3, b1, b3, Wout,
            W1f, W2f, W3f, W1g, W34, b34, PK, qidx, cnt_j, cnt_k, rank_j, rank_k);
        scan_kernel<<<2, 1024, 0, stream>>>(cnt_j, cnt_k, off_j, off_k);
        permute_kernel<<<(N_DIH + 255) / 256, 256, 0, stream>>>(
            qidx, off_j, off_k, rank_j, rank_k, perm_j, perm_k);
        uv_kernel<<<(UVW + 3) / 4, 256, 0, stream>>>(x, W1g, uvp);
        mlp2_kernel<<<NW16 / 4, 256, 0, stream>>>(uvp, qidx, attr, PK, W2f, b2, h2);
        aggregate_out64<<<(N_NODES + ATILE - 1) / ATILE, 256, 0, stream>>>(
            h2, off_j, off_k, perm_j, perm_k, W34, b34, out);
    } else if (words >= (size_t)41100000) {
        // ---- tier B: round-1 path ----
        size_t o = 0;
        unsigned short* h2  = (unsigned short*)wsf;          o += 32000000;
        unsigned short* xb  = (unsigned short*)(wsf + o);    o += 6400000;
        unsigned short* W1f = (unsigned short*)(wsf + o);    o += 8192;
        unsigned short* W2f = (unsigned short*)(wsf + o);    o += 2048;
        unsigned short* W3f = (unsigned short*)(wsf + o);    o += 4096;
        float* W34  = wsf + o;                               o += 8192;
        float* b34  = wsf + o;                               o += 128;
        int* cnt_j  = (int*)(wsf + o);                       o += 100000;
        int* cnt_k  = (int*)(wsf + o);                       o += 100000;
        int* off_j  = (int*)(wsf + o);                       o += 100001;
        int* off_k  = (int*)(wsf + o);                       o += 100001;
        int* perm_j = (int*)(wsf + o);                       o += 1000000;
        int* perm_k = (int*)(wsf + o);                       o += 1000000;
        unsigned short* W1g = (unsigned short*)(wsf + o);    o += 8192;
        float* PK   = wsf + o;                               o += 256;
        int* rank_j = (int*)h2;
        int* rank_k = rank_j + N_DIH;

        hipMemsetAsync(cnt_j, 0, (size_t)200000 * sizeof(int), stream);
        prep_kernel<<<PREP_ALL, 256, 0, stream>>>(
            x, xb, W1, W2, W3, b1, b3, Wout,
            W1f, W2f, W3f, W1g, W34, b34, PK, qidx, cnt_j, cnt_k, rank_j, rank_k);
        scan_kernel<<<2, 1024, 0, stream>>>(cnt_j, cnt_k, off_j, off_k);
        permute_kernel<<<(N_DIH + 255) / 256, 256, 0, stream>>>(
            qidx, off_j, off_k, rank_j, rank_k, perm_j, perm_k);
        mlp12_kernel<<<NW16 / 4, 256, 0, stream>>>(
            xb, qidx, attr, W1, b1, b2, W1f, W2f, h2);
        aggregate_out64<<<(N_NODES + ATILE - 1) / ATILE, 256, 0, stream>>>(
            h2, off_j, off_k, perm_j, perm_k, W34, b34, out);
    } else {
        // ---- tier C: proven atomic fallback (78.5 MB) ----
        int*   cnt_j   = (int*)wsf;
        int*   cnt_k   = cnt_j + N_NODES;
        float* scale_j = wsf + 200000;
        float* scale_k = wsf + 300000;
        float* aggr    = wsf + 400000;
        unsigned short* xb  = (unsigned short*)(wsf + 13200000);
        unsigned short* W1f = (unsigned short*)(wsf + 19600000);
        unsigned short* W2f = (unsigned short*)(wsf + 19608192);
        unsigned short* W3f = (unsigned short*)(wsf + 19610240);
        float* W34 = wsf + 19612288;   // scratch (unused result ok)
        float* b34 = wsf + 19612288;   // overlap fine for fallback
        unsigned short* W1g = (unsigned short*)(wsf + 19612288); // scratch overlap
        float* PK  = wsf + 19612288;   // scratch overlap

        hipMemsetAsync(cnt_j, 0, (size_t)2 * N_NODES * sizeof(int), stream);
        hipMemsetAsync(aggr, 0, (size_t)N_NODES * 128 * sizeof(float), stream);
        prep_kernel<<<PREP_ALL, 256, 0, stream>>>(
            x, xb, W1, W2, W3, b1, b3, Wout,
            W1f, W2f, W3f, W1g, W34, b34, PK, qidx, cnt_j, cnt_k, nullptr, nullptr);
        scale_kernel<<<(N_NODES + 255) / 256, 256, 0, stream>>>(cnt_j, cnt_k, scale_j, scale_k);
        mlp_mfma_atomic<<<(NWAVES + 3) / 4, 256, 0, stream>>>(
            xb, qidx, attr, W1, b1, b2, b3, W1f, W2f, W3f, scale_j, scale_k, aggr);
        out_kernel<<<(N_NODES + OTILE - 1) / OTILE, OB, 0, stream>>>(aggr, Wout, out);
    }
}

// Round 9
// 536.327 us; speedup vs baseline: 1.1320x; 1.1320x over previous
//
#include <hip/hip_runtime.h>

#define N_NODES    100000
#define N_DIH      1000000
#define SCALAR_DIM 128
#define HIDDEN     64
#define ATTR_DIM   3

typedef short v8s __attribute__((ext_vector_type(8)));
typedef float v4f __attribute__((ext_vector_type(4)));
typedef _Float16 v8h __attribute__((ext_vector_type(8)));

__device__ __forceinline__ float silu(float v) {
    return __fdividef(v, 1.0f + __expf(-v));
}

__device__ __forceinline__ unsigned short bf16_rne(float f) {
    unsigned int u = __float_as_uint(f);
    u = (u + 0x7FFFu + ((u >> 16) & 1u)) >> 16;
    return (unsigned short)u;
}

__device__ __forceinline__ float2 bf2_to_f2(unsigned int v) {
    float2 r;
    r.x = __uint_as_float(v << 16);
    r.y = __uint_as_float(v & 0xffff0000u);
    return r;
}

// ---------------- prep ----------------
#define PREP_W   112
#define PREP_W34 33
#define PREP_G   64
#define PREP_H   3907
#define PREP_XB  12500
#define PREP_MAIN (PREP_W + PREP_W34 + PREP_G + PREP_H)
#define PREP_ALL  (PREP_MAIN + PREP_XB)

__global__ void prep_kernel(const float* __restrict__ x, unsigned short* __restrict__ xb,
                            const float* __restrict__ W1, const float* __restrict__ W2,
                            const float* __restrict__ W3, const float* __restrict__ b1,
                            const float* __restrict__ b3,
                            const float* __restrict__ Wout,
                            unsigned short* __restrict__ W1f, unsigned short* __restrict__ W2f,
                            unsigned short* __restrict__ W3f, unsigned short* __restrict__ W1g,
                            float* __restrict__ W34, float* __restrict__ b34,
                            float* __restrict__ PK,
                            const int* __restrict__ qidx,
                            int* __restrict__ cnt_j, int* __restrict__ cnt_k,
                            int* __restrict__ rank_j, int* __restrict__ rank_k) {
    const int b = blockIdx.x;
    if (b < PREP_W) {
        const int tid = b * 256 + threadIdx.x;
        if (tid < 16384) {                     // W1f: kc<8, nt<4
            const int j = tid & 7, lane = (tid >> 3) & 63, t = tid >> 9;
            const int k = (t >> 2) * 32 + ((lane >> 4) << 3) + j;
            const int n = (t & 3) * 16 + (lane & 15);
            W1f[tid] = bf16_rne(W1[k * 64 + n]);
        } else if (tid < 20480) {              // W2f: kc<2, nt<4
            const int i = tid - 16384;
            const int j = i & 7, lane = (i >> 3) & 63, t = i >> 9;
            const int k = (t >> 2) * 32 + ((lane >> 4) << 3) + j;
            const int n = (t & 3) * 16 + (lane & 15);
            W2f[i] = bf16_rne(W2[k * 64 + n]);
        } else if (tid < 28672) {              // W3f (fallback path only)
            const int i = tid - 20480;
            const int j = i & 7, lane = (i >> 3) & 63, t = i >> 9;
            const int k = (t >> 3) * 32 + ((lane >> 4) << 3) + j;
            const int n = (t & 7) * 16 + (lane & 15);
            W3f[i] = bf16_rne(W3[k * 128 + n]);
        }
    } else if (b < PREP_W + PREP_W34) {
        const int t34 = (b - PREP_W) * 256 + threadIdx.x;
        if (t34 < 8192) {                      // W34[r][c] = sum_m W3[r][m]*Wout[m][c]
            const int r = t34 >> 7, c = t34 & 127;
            float s = 0.f;
            #pragma unroll 4
            for (int m = 0; m < 128; ++m) s += W3[r * 128 + m] * Wout[m * 128 + c];
            W34[t34] = s;
        } else if (t34 < 8320) {               // b34[c] = sum_m b3[m]*Wout[m][c]
            const int c = t34 - 8192;
            float s = 0.f;
            #pragma unroll 4
            for (int m = 0; m < 128; ++m) s += b3[m] * Wout[m * 128 + c];
            b34[c] = s;
        } else if (t34 < 8384) {               // PK[c] = {wa0, wa1, wa2, b1}
            const int c = t34 - 8320;
            PK[c * 4 + 0] = W1[256 * 64 + c];
            PK[c * 4 + 1] = W1[257 * 64 + c];
            PK[c * 4 + 2] = W1[258 * 64 + c];
            PK[c * 4 + 3] = b1[c];
        }
    } else if (b < PREP_W + PREP_W34 + PREP_G) {
        // W1g: B-frag pack of W' (128x128), W'[k][n] = n<64 ? W1a[k][n] : W1b[k][n-64]
        const int i = (b - PREP_W - PREP_W34) * 256 + threadIdx.x;   // < 16384
        const int j = i & 7, lane = (i >> 3) & 63, t = i >> 9;       // t < 32
        const int k = (t >> 3) * 32 + ((lane >> 4) << 3) + j;        // k < 128
        const int n = (t & 7) * 16 + (lane & 15);                    // n < 128
        const float w = (n < 64) ? W1[k * 64 + n] : W1[(128 + k) * 64 + (n - 64)];
        W1g[i] = bf16_rne(w);
    } else if (b < PREP_MAIN) {
        const int t = (b - PREP_W - PREP_W34 - PREP_G) * 256 + threadIdx.x;
        if (t < N_DIH) {
            const int rj = atomicAdd(&cnt_j[qidx[N_DIH + t]], 1);
            const int rk = atomicAdd(&cnt_k[qidx[2 * N_DIH + t]], 1);
            if (rank_j != nullptr) {           // uniform branch; fallback passes null
                rank_j[t] = rj;
                rank_k[t] = rk;
            }
        }
    } else {
        const int t = (b - PREP_MAIN) * 256 + threadIdx.x;           // < 3.2M
        const float4 v = *(const float4*)&x[(size_t)t * 4];
        ushort4 o;
        o.x = bf16_rne(v.x); o.y = bf16_rne(v.y); o.z = bf16_rne(v.z); o.w = bf16_rne(v.w);
        *(ushort4*)&xb[(size_t)t * 4] = o;
    }
}

// ---------------- scan: exclusive prefix over counts -> off ----------------
__global__ __launch_bounds__(1024) void scan_kernel(const int* __restrict__ cnt_j,
                                                    const int* __restrict__ cnt_k,
                                                    int* __restrict__ off_j, int* __restrict__ off_k) {
    const int* cnt = blockIdx.x ? cnt_k : cnt_j;
    int* off = blockIdx.x ? off_k : off_j;
    __shared__ int wtot[17];
    const int tid = threadIdx.x, lane = tid & 63, wv = tid >> 6;
    int carry = 0;
    for (int base = 0; base < N_NODES; base += 1024) {
        const int i = base + tid;
        const int v = (i < N_NODES) ? cnt[i] : 0;
        int inc = v;
        #pragma unroll
        for (int o = 1; o < 64; o <<= 1) {
            const int t = __shfl_up(inc, o);
            if (lane >= o) inc += t;
        }
        if (lane == 63) wtot[wv] = inc;
        __syncthreads();
        if (tid == 0) {
            int run = 0;
            #pragma unroll
            for (int w = 0; w < 16; ++w) { const int t = wtot[w]; wtot[w] = run; run += t; }
            wtot[16] = run;
        }
        __syncthreads();
        const int excl = inc - v + wtot[wv] + carry;
        if (i < N_NODES) off[i] = excl;
        carry += wtot[16];
        __syncthreads();
    }
    if (tid == 0) off[N_NODES] = carry;
}

// ---------------- permute: atomic-free scatter using captured ranks ----------------
__global__ void permute_kernel(const int* __restrict__ qidx,
                               const int* __restrict__ off_j, const int* __restrict__ off_k,
                               const int* __restrict__ rank_j, const int* __restrict__ rank_k,
                               int* __restrict__ perm_j, int* __restrict__ perm_k) {
    const int t = blockIdx.x * blockDim.x + threadIdx.x;
    if (t < N_DIH) {
        const int j = qidx[N_DIH + t];
        perm_j[off_j[j] + rank_j[t]] = t;
        const int k = qidx[2 * N_DIH + t];
        perm_k[off_k[k] + rank_k[t]] = t;
    }
}

// ========== uv: per-node partials U = x@W1a, V = x@W1b (f16, row = [U|V]) ==========
#define UVW 3125    // 100000 / 32 rows per wave

__global__ __launch_bounds__(256, 4) void uv_kernel(
    const float* __restrict__ x, const unsigned short* __restrict__ W1g,
    _Float16* __restrict__ uv)
{
    const int tid = threadIdx.x, lane = tid & 63, wv = tid >> 6;
    const int g = blockIdx.x * 4 + wv;
    if (g >= UVW) return;
    const int D0 = g * 32;
    const int m16 = lane & 15, quad = lane >> 4;
    const int r0 = D0 + m16, r1 = D0 + 16 + m16;

    v4f acc[2][8];
    #pragma unroll
    for (int mt = 0; mt < 2; ++mt)
        #pragma unroll
        for (int nt = 0; nt < 8; ++nt) acc[mt][nt] = (v4f){0.f, 0.f, 0.f, 0.f};

    #pragma unroll
    for (int kc = 0; kc < 4; ++kc) {
        const int co = kc * 32 + quad * 8;
        v8s a0, a1;
        {
            const float4 f0 = *(const float4*)&x[(size_t)r0 * 128 + co];
            const float4 f1 = *(const float4*)&x[(size_t)r0 * 128 + co + 4];
            a0[0] = (short)bf16_rne(f0.x); a0[1] = (short)bf16_rne(f0.y);
            a0[2] = (short)bf16_rne(f0.z); a0[3] = (short)bf16_rne(f0.w);
            a0[4] = (short)bf16_rne(f1.x); a0[5] = (short)bf16_rne(f1.y);
            a0[6] = (short)bf16_rne(f1.z); a0[7] = (short)bf16_rne(f1.w);
        }
        {
            const float4 f0 = *(const float4*)&x[(size_t)r1 * 128 + co];
            const float4 f1 = *(const float4*)&x[(size_t)r1 * 128 + co + 4];
            a1[0] = (short)bf16_rne(f0.x); a1[1] = (short)bf16_rne(f0.y);
            a1[2] = (short)bf16_rne(f0.z); a1[3] = (short)bf16_rne(f0.w);
            a1[4] = (short)bf16_rne(f1.x); a1[5] = (short)bf16_rne(f1.y);
            a1[6] = (short)bf16_rne(f1.z); a1[7] = (short)bf16_rne(f1.w);
        }
        #pragma unroll
        for (int nt = 0; nt < 8; ++nt) {
            const v8s bf = *(const v8s*)(W1g + ((kc * 8 + nt) * 64 + lane) * 8);
            acc[0][nt] = __builtin_amdgcn_mfma_f32_16x16x32_bf16(a0, bf, acc[0][nt], 0, 0, 0);
            acc[1][nt] = __builtin_amdgcn_mfma_f32_16x16x32_bf16(a1, bf, acc[1][nt], 0, 0, 0);
        }
    }
    #pragma unroll
    for (int mt = 0; mt < 2; ++mt)
        #pragma unroll
        for (int nt = 0; nt < 8; ++nt) {
            const int c = nt * 16 + m16;
            #pragma unroll
            for (int reg = 0; reg < 4; ++reg) {
                const int n = D0 + mt * 16 + quad * 4 + reg;
                uv[(size_t)n * 128 + c] = (_Float16)acc[mt][nt][reg];
            }
        }
}

#define NW16 62500   // 1e6 / 16 dihedrals per wave

// ========== mlp2s (tier A'): MLP + scatter rows into j-sorted and k-sorted order ==========
__global__ __launch_bounds__(256, 6) void mlp2s_kernel(
    const _Float16* __restrict__ uv, const int* __restrict__ qidx,
    const float* __restrict__ attr, const float* __restrict__ PK,
    const unsigned short* __restrict__ W2f, const float* __restrict__ b2,
    const int* __restrict__ off_j, const int* __restrict__ off_k,
    const int* __restrict__ rank_j, const int* __restrict__ rank_k,
    unsigned short* __restrict__ h2j, unsigned short* __restrict__ h2k)
{
    __shared__ __align__(16) unsigned short hbuf[4][1024];   // per wave: row staging
    const int tid = threadIdx.x, lane = tid & 63, wv = tid >> 6;
    const int g = blockIdx.x * 4 + wv;                       // grid exact: no guard
    const int D0 = g * 16;
    const int m16 = lane & 15, quad = lane >> 4;
    unsigned short* hs = hbuf[wv];

    const int d = D0 + m16;
    const int irow = qidx[d];
    const int lrow = qidx[3 * N_DIH + d];
    const int jn = qidx[N_DIH + d];
    const int kn = qidx[2 * N_DIH + d];
    const int pj = off_j[jn] + rank_j[d];
    const int pk = off_k[kn] + rank_k[d];

    const _Float16* up = uv + (size_t)irow * 128 + quad * 8;       // U part: cols [0,64)
    const _Float16* vp = uv + (size_t)lrow * 128 + 64 + quad * 8;  // V part: cols [64,128)
    const v8h u0 = *(const v8h*)(up + 0);
    const v8h u1 = *(const v8h*)(up + 32);
    const v8h w0 = *(const v8h*)(vp + 0);
    const v8h w1 = *(const v8h*)(vp + 32);
    const float a0 = attr[(size_t)d * 3 + 0];
    const float a1 = attr[(size_t)d * 3 + 1];
    const float a2 = attr[(size_t)d * 3 + 2];

    const int cb = quad * 8;
    v8s af0, af1;
    #pragma unroll
    for (int e = 0; e < 8; ++e) {
        const float4 pk0 = *(const float4*)&PK[(size_t)(cb + e) * 4];
        const float s0 = (float)u0[e] + (float)w0[e] + pk0.x * a0 + pk0.y * a1 + pk0.z * a2 + pk0.w;
        af0[e] = (short)bf16_rne(silu(s0));
        const float4 pk1 = *(const float4*)&PK[(size_t)(32 + cb + e) * 4];
        const float s1 = (float)u1[e] + (float)w1[e] + pk1.x * a0 + pk1.y * a1 + pk1.z * a2 + pk1.w;
        af1[e] = (short)bf16_rne(silu(s1));
    }

    v4f acc2[4];
    #pragma unroll
    for (int nt = 0; nt < 4; ++nt) acc2[nt] = (v4f){0.f, 0.f, 0.f, 0.f};
    #pragma unroll
    for (int nt = 0; nt < 4; ++nt) {
        const v8s bA = *(const v8s*)(W2f + ((nt) * 64 + lane) * 8);
        const v8s bB = *(const v8s*)(W2f + ((4 + nt) * 64 + lane) * 8);
        acc2[nt] = __builtin_amdgcn_mfma_f32_16x16x32_bf16(af0, bA, acc2[nt], 0, 0, 0);
        acc2[nt] = __builtin_amdgcn_mfma_f32_16x16x32_bf16(af1, bB, acc2[nt], 0, 0, 0);
    }

    #pragma unroll
    for (int nt = 0; nt < 4; ++nt) {
        const int c = nt * 16 + m16;
        const float b2c = b2[c];
        #pragma unroll
        for (int reg = 0; reg < 4; ++reg) {
            const int row = quad * 4 + reg;
            hs[row * 64 + c] = bf16_rne(silu(acc2[nt][reg] + b2c));
        }
    }
    const int sub = lane & 7;
    #pragma unroll
    for (int i = 0; i < 2; ++i) {
        const int row = i * 8 + (lane >> 3);
        const int pjr = __shfl(pj, row);
        const int pkr = __shfl(pk, row);
        const v8s rowv = *(const v8s*)(hs + i * 512 + lane * 8);
        *(v8s*)(h2j + (size_t)pjr * 64 + sub * 8) = rowv;
        *(v8s*)(h2k + (size_t)pkr * 64 + sub * 8) = rowv;
    }
}

// ========== mlp2 (tier A): gather f16 uv rows, layer-1 finish, layer-2 MFMA -> h2 ==========
__global__ __launch_bounds__(256, 8) void mlp2_kernel(
    const _Float16* __restrict__ uv, const int* __restrict__ qidx,
    const float* __restrict__ attr, const float* __restrict__ PK,
    const unsigned short* __restrict__ W2f, const float* __restrict__ b2,
    unsigned short* __restrict__ h2)
{
    __shared__ __align__(16) unsigned short hbuf[4][1024];   // per wave: h2 row staging
    const int tid = threadIdx.x, lane = tid & 63, wv = tid >> 6;
    const int g = blockIdx.x * 4 + wv;                       // grid exact: no guard
    const int D0 = g * 16;
    const int m16 = lane & 15, quad = lane >> 4;
    unsigned short* hs = hbuf[wv];

    const int d = D0 + m16;
    const int irow = qidx[d];
    const int lrow = qidx[3 * N_DIH + d];

    const _Float16* up = uv + (size_t)irow * 128 + quad * 8;       // U part: cols [0,64)
    const _Float16* vp = uv + (size_t)lrow * 128 + 64 + quad * 8;  // V part: cols [64,128)
    const v8h u0 = *(const v8h*)(up + 0);
    const v8h u1 = *(const v8h*)(up + 32);
    const v8h w0 = *(const v8h*)(vp + 0);
    const v8h w1 = *(const v8h*)(vp + 32);
    const float a0 = attr[(size_t)d * 3 + 0];
    const float a1 = attr[(size_t)d * 3 + 1];
    const float a2 = attr[(size_t)d * 3 + 2];

    const int cb = quad * 8;
    v8s af0, af1;
    #pragma unroll
    for (int e = 0; e < 8; ++e) {
        const float4 pk0 = *(const float4*)&PK[(size_t)(cb + e) * 4];
        const float s0 = (float)u0[e] + (float)w0[e] + pk0.x * a0 + pk0.y * a1 + pk0.z * a2 + pk0.w;
        af0[e] = (short)bf16_rne(silu(s0));
        const float4 pk1 = *(const float4*)&PK[(size_t)(32 + cb + e) * 4];
        const float s1 = (float)u1[e] + (float)w1[e] + pk1.x * a0 + pk1.y * a1 + pk1.z * a2 + pk1.w;
        af1[e] = (short)bf16_rne(silu(s1));
    }

    v4f acc2[4];
    #pragma unroll
    for (int nt = 0; nt < 4; ++nt) acc2[nt] = (v4f){0.f, 0.f, 0.f, 0.f};
    #pragma unroll
    for (int nt = 0; nt < 4; ++nt) {
        const v8s bA = *(const v8s*)(W2f + ((nt) * 64 + lane) * 8);
        const v8s bB = *(const v8s*)(W2f + ((4 + nt) * 64 + lane) * 8);
        acc2[nt] = __builtin_amdgcn_mfma_f32_16x16x32_bf16(af0, bA, acc2[nt], 0, 0, 0);
        acc2[nt] = __builtin_amdgcn_mfma_f32_16x16x32_bf16(af1, bB, acc2[nt], 0, 0, 0);
    }

    #pragma unroll
    for (int nt = 0; nt < 4; ++nt) {
        const int c = nt * 16 + m16;
        const float b2c = b2[c];
        #pragma unroll
        for (int reg = 0; reg < 4; ++reg) {
            const int row = quad * 4 + reg;
            hs[row * 64 + c] = bf16_rne(silu(acc2[nt][reg] + b2c));
        }
    }
    #pragma unroll
    for (int i = 0; i < 2; ++i) {
        const v8s row16 = *(const v8s*)(hs + i * 512 + lane * 8);
        *(v8s*)(h2 + (size_t)D0 * 64 + i * 512 + lane * 8) = row16;
    }
}

// ========== tier-B MLP (kept verbatim for smaller workspaces) ==========
#define NWAVES 31250    // 1e6 / 32

__global__ __launch_bounds__(256, 8) void mlp12_kernel(
    const unsigned short* __restrict__ xb, const int* __restrict__ qidx,
    const float* __restrict__ attr,
    const float* __restrict__ W1, const float* __restrict__ b1,
    const float* __restrict__ b2,
    const unsigned short* __restrict__ W1f, const unsigned short* __restrict__ W2f,
    unsigned short* __restrict__ h2)
{
    __shared__ __align__(16) unsigned short hbuf[4][1024];
    const int tid  = threadIdx.x;
    const int lane = tid & 63;
    const int wv   = tid >> 6;
    const int g    = blockIdx.x * 4 + wv;
    const int D0   = g * 16;
    const int m16  = lane & 15;
    const int quad = lane >> 4;
    unsigned short* hs = hbuf[wv];

    const int irow = qidx[D0 + m16];
    const int lrow = qidx[3 * N_DIH + D0 + m16];

    v4f acc[4];
    #pragma unroll
    for (int nt = 0; nt < 4; ++nt) acc[nt] = (v4f){0.f, 0.f, 0.f, 0.f};

    #pragma unroll
    for (int kc = 0; kc < 8; ++kc) {
        const int side = kc >> 2;
        const int coff = (kc & 3) * 32 + quad * 8;
        const int r0 = side ? lrow : irow;
        const v8s a0 = *(const v8s*)(xb + (size_t)r0 * 128 + coff);
        #pragma unroll
        for (int nt = 0; nt < 4; ++nt) {
            const v8s b = *(const v8s*)(W1f + ((kc * 4 + nt) * 64 + lane) * 8);
            acc[nt] = __builtin_amdgcn_mfma_f32_16x16x32_bf16(a0, b, acc[nt], 0, 0, 0);
        }
    }

    #pragma unroll
    for (int nt = 0; nt < 4; ++nt) {
        const int c = nt * 16 + m16;
        const float b1c = b1[c];
        const float wa0 = W1[256 * 64 + c];
        const float wa1 = W1[257 * 64 + c];
        const float wa2 = W1[258 * 64 + c];
        const int quadp = (nt * 2 + (m16 >> 3)) & 3;
        const int jp    = m16 & 7;
        const int kc2   = nt >> 1;
        #pragma unroll
        for (int reg = 0; reg < 4; ++reg) {
            const int r = quad * 4 + reg;
            const int d = D0 + r;
            float v = acc[nt][reg] + b1c
                    + attr[(size_t)d * 3 + 0] * wa0
                    + attr[(size_t)d * 3 + 1] * wa1
                    + attr[(size_t)d * 3 + 2] * wa2;
            v = silu(v);
            hs[kc2 * 512 + (r + 16 * quadp) * 8 + jp] = bf16_rne(v);
        }
    }

    v4f acc2[4];
    #pragma unroll
    for (int nt = 0; nt < 4; ++nt) acc2[nt] = (v4f){0.f, 0.f, 0.f, 0.f};

    #pragma unroll
    for (int kc = 0; kc < 2; ++kc) {
        const v8s a0 = *(const v8s*)(hs + kc * 512 + lane * 8);
        #pragma unroll
        for (int nt = 0; nt < 4; ++nt) {
            const v8s b = *(const v8s*)(W2f + ((kc * 4 + nt) * 64 + lane) * 8);
            acc2[nt] = __builtin_amdgcn_mfma_f32_16x16x32_bf16(a0, b, acc2[nt], 0, 0, 0);
        }
    }

    #pragma unroll
    for (int nt = 0; nt < 4; ++nt) {
        const int c = nt * 16 + m16;
        const float b2c = b2[c];
        #pragma unroll
        for (int reg = 0; reg < 4; ++reg) {
            const int row = quad * 4 + reg;
            hs[row * 64 + c] = bf16_rne(silu(acc2[nt][reg] + b2c));
        }
    }
    #pragma unroll
    for (int i = 0; i < 2; ++i) {
        const v8s row16 = *(const v8s*)(hs + i * 512 + lane * 8);
        *(v8s*)(h2 + (size_t)D0 * 64 + i * 512 + lane * 8) = row16;
    }
}

// ====== aggregate (tier A'): STREAMING reads of pre-sorted h2j/h2k + fused W34 GEMM ======
__global__ __launch_bounds__(256, 2) void aggregate_seq(
    const unsigned short* __restrict__ h2j, const unsigned short* __restrict__ h2k,
    const int* __restrict__ off_j, const int* __restrict__ off_k,
    const float* __restrict__ W34, const float* __restrict__ b34,
    float* __restrict__ out)
{
    __shared__ float a_lds[64 * 132];
    const int tid    = threadIdx.x;
    const int lane   = tid & 63;
    const int wv     = __builtin_amdgcn_readfirstlane(tid >> 6);
    const int base   = blockIdx.x * 64;
    const int half   = lane >> 5;
    const int lane31 = lane & 31;

    for (int p = 0; p < 16; ++p) {
        const int ln = wv * 16 + p;
        const int n  = base + ln;
        float sx = 0.f, sy = 0.f, bf = 0.f;
        if (n < N_NODES) {
            int cj, ck;
            {
                const int e0 = off_j[n], e1 = off_j[n + 1];
                cj = e1 - e0;
                float ax = 0.f, ay = 0.f;
                int e = e0;
                for (; e + 4 <= e1; e += 4) {
                    const float2 fA = bf2_to_f2(*(const unsigned int*)(h2j + (size_t)(e + half) * 64 + lane31 * 2));
                    const float2 fB = bf2_to_f2(*(const unsigned int*)(h2j + (size_t)(e + 2 + half) * 64 + lane31 * 2));
                    ax += fA.x + fB.x; ay += fA.y + fB.y;
                }
                if (e + 2 <= e1) {
                    const float2 f = bf2_to_f2(*(const unsigned int*)(h2j + (size_t)(e + half) * 64 + lane31 * 2));
                    ax += f.x; ay += f.y;
                    e += 2;
                }
                if (e < e1 && half == 0) {
                    const float2 f = bf2_to_f2(*(const unsigned int*)(h2j + (size_t)e * 64 + lane31 * 2));
                    ax += f.x; ay += f.y;
                }
                ax += __shfl_xor(ax, 32);
                ay += __shfl_xor(ay, 32);
                const float inv = 1.0f / (float)max(cj, 1);
                sx += ax * inv; sy += ay * inv;
            }
            {
                const int e0 = off_k[n], e1 = off_k[n + 1];
                ck = e1 - e0;
                float ax = 0.f, ay = 0.f;
                int e = e0;
                for (; e + 4 <= e1; e += 4) {
                    const float2 fA = bf2_to_f2(*(const unsigned int*)(h2k + (size_t)(e + half) * 64 + lane31 * 2));
                    const float2 fB = bf2_to_f2(*(const unsigned int*)(h2k + (size_t)(e + 2 + half) * 64 + lane31 * 2));
                    ax += fA.x + fB.x; ay += fA.y + fB.y;
                }
                if (e + 2 <= e1) {
                    const float2 f = bf2_to_f2(*(const unsigned int*)(h2k + (size_t)(e + half) * 64 + lane31 * 2));
                    ax += f.x; ay += f.y;
                    e += 2;
                }
                if (e < e1 && half == 0) {
                    const float2 f = bf2_to_f2(*(const unsigned int*)(h2k + (size_t)e * 64 + lane31 * 2));
                    ax += f.x; ay += f.y;
                }
                ax += __shfl_xor(ax, 32);
                ay += __shfl_xor(ay, 32);
                const float inv = 1.0f / (float)max(ck, 1);
                sx += ax * inv; sy += ay * inv;
            }
            bf = 0.5f * ((float)(cj > 0) + (float)(ck > 0));
        }
        if (half == 0) {
            float2 w; w.x = sx * 0.5f; w.y = sy * 0.5f;
            *(float2*)&a_lds[ln * 132 + 2 * lane31] = w;
            if (lane31 == 0) a_lds[ln * 132 + 128] = bf;
        }
    }
    __syncthreads();

    const int co = wv * 32;
    const float bfv = a_lds[lane * 132 + 128];
    float acc[32];
    #pragma unroll
    for (int c = 0; c < 32; ++c) acc[c] = bfv * b34[co + c];
    const float* ap = &a_lds[lane * 132];
    #pragma unroll 2
    for (int d = 0; d < 64; d += 4) {
        const float4 av = *(const float4*)&ap[d];
        const float* w0 = &W34[(d + 0) * 128 + co];
        const float* w1 = w0 + 128;
        const float* w2 = w0 + 256;
        const float* w3 = w0 + 384;
        #pragma unroll
        for (int c = 0; c < 32; ++c)
            acc[c] += av.x * w0[c] + av.y * w1[c] + av.z * w2[c] + av.w * w3[c];
    }
    __syncthreads();
    #pragma unroll
    for (int c = 0; c < 32; c += 4)
        *(float4*)&a_lds[lane * 132 + co + c] = make_float4(acc[c], acc[c+1], acc[c+2], acc[c+3]);
    __syncthreads();
    const int q4 = lane31 << 2;
    #pragma unroll
    for (int p = 0; p < 8; ++p) {
        const int ln = wv * 16 + p * 2 + half;
        const int n  = base + ln;
        if (n < N_NODES)
            *(float4*)&out[(size_t)n * 128 + q4] = *(const float4*)&a_lds[ln * 132 + q4];
    }
}

// ====== aggregate (tier A/B): R7-proven half-wave-per-node gather + j/k interleave ======
// R9: reverted R8's shfl-prefetch/32-tile (regression: serialized load issue via
// LDS-pipe dependency + L2 thrash). Back to R7 structure; ONE change: the j and
// k lists are independent streams, so the main loop issues 8 j-rows + 8 k-rows
// together (16 in flight per half vs 8) using the same proven load idiom.
__global__ __launch_bounds__(256, 4) void aggregate_out64(
    const unsigned short* __restrict__ h2,
    const int* __restrict__ off_j, const int* __restrict__ off_k,
    const int* __restrict__ perm_j, const int* __restrict__ perm_k,
    const float* __restrict__ W34, const float* __restrict__ b34,
    float* __restrict__ out)
{
    __shared__ float a_lds[64 * 132];   // [node][0..63]=aggH, [128]=bias flag
    const int tid    = threadIdx.x;
    const int lane   = tid & 63;
    const int wv     = __builtin_amdgcn_readfirstlane(tid >> 6);  // 0..3
    const int base   = blockIdx.x * 64;
    const int half   = lane >> 5;
    const int lane31 = lane & 31;

#define AGG_BATCH(B, permp, e, e1, ax, ay) \
    if (e + B <= e1) { \
        int dd[B]; \
        _Pragma("unroll") \
        for (int q = 0; q < B; ++q) dd[q] = permp[e + q]; \
        unsigned int rr[B]; \
        _Pragma("unroll") \
        for (int q = 0; q < B; ++q) \
            rr[q] = *(const unsigned int*)(h2 + (size_t)dd[q] * 64 + lane31 * 2); \
        _Pragma("unroll") \
        for (int q = 0; q < B; ++q) { \
            const float2 f = bf2_to_f2(rr[q]); \
            ax += f.x; ay += f.y; \
        } \
        e += B; \
    }

    // phase 1: half-wave h of wave wv aggregates nodes base + wv*16 + p*2 + h
    for (int p = 0; p < 8; ++p) {
        const int ln = wv * 16 + p * 2 + half;
        const int n  = base + ln;
        float sx = 0.f, sy = 0.f, bf = 0.f;
        if (n < N_NODES) {
            const int ej0 = off_j[n], ej1 = off_j[n + 1];
            const int ek0 = off_k[n], ek1 = off_k[n + 1];
            const int cj = ej1 - ej0, ck = ek1 - ek0;
            float axj = 0.f, ayj = 0.f, axk = 0.f, ayk = 0.f;
            int ej = ej0, ek = ek0;
            // combined main loop: 8 j-rows + 8 k-rows in flight together
            while (ej + 8 <= ej1 && ek + 8 <= ek1) {
                int dj[8], dk[8];
                #pragma unroll
                for (int q = 0; q < 8; ++q) { dj[q] = perm_j[ej + q]; dk[q] = perm_k[ek + q]; }
                unsigned int rj[8], rk[8];
                #pragma unroll
                for (int q = 0; q < 8; ++q) {
                    rj[q] = *(const unsigned int*)(h2 + (size_t)dj[q] * 64 + lane31 * 2);
                    rk[q] = *(const unsigned int*)(h2 + (size_t)dk[q] * 64 + lane31 * 2);
                }
                #pragma unroll
                for (int q = 0; q < 8; ++q) {
                    const float2 fj = bf2_to_f2(rj[q]); axj += fj.x; ayj += fj.y;
                    const float2 fk = bf2_to_f2(rk[q]); axk += fk.x; ayk += fk.y;
                }
                ej += 8; ek += 8;
            }
            // drain j tail (8/4/2/1)
            for (; ej + 8 <= ej1; ) { AGG_BATCH(8, perm_j, ej, ej1, axj, ayj) }
            AGG_BATCH(4, perm_j, ej, ej1, axj, ayj)
            AGG_BATCH(2, perm_j, ej, ej1, axj, ayj)
            AGG_BATCH(1, perm_j, ej, ej1, axj, ayj)
            // drain k tail (8/4/2/1)
            for (; ek + 8 <= ek1; ) { AGG_BATCH(8, perm_k, ek, ek1, axk, ayk) }
            AGG_BATCH(4, perm_k, ek, ek1, axk, ayk)
            AGG_BATCH(2, perm_k, ek, ek1, axk, ayk)
            AGG_BATCH(1, perm_k, ek, ek1, axk, ayk)
            const float invj = 1.0f / (float)max(cj, 1);
            const float invk = 1.0f / (float)max(ck, 1);
            sx = axj * invj + axk * invk;
            sy = ayj * invj + ayk * invk;
            bf = 0.5f * ((float)(cj > 0) + (float)(ck > 0));
        }
        float2 w; w.x = sx * 0.5f; w.y = sy * 0.5f;
        *(float2*)&a_lds[ln * 132 + 2 * lane31] = w;
        if (lane31 == 0) a_lds[ln * 132 + 128] = bf;
    }
#undef AGG_BATCH
    __syncthreads();

    // phase 2: out[n] = aggH[n] @ W34 + bf*b34  (lane = node, W34 via scalar loads)
    const int co = wv * 32;
    const float bfv = a_lds[lane * 132 + 128];
    float acc[32];
    #pragma unroll
    for (int c = 0; c < 32; ++c) acc[c] = bfv * b34[co + c];
    const float* ap = &a_lds[lane * 132];
    #pragma unroll 2
    for (int d = 0; d < 64; d += 4) {
        const float4 av = *(const float4*)&ap[d];
        const float* w0 = &W34[(d + 0) * 128 + co];
        const float* w1 = w0 + 128;
        const float* w2 = w0 + 256;
        const float* w3 = w0 + 384;
        #pragma unroll
        for (int c = 0; c < 32; ++c)
            acc[c] += av.x * w0[c] + av.y * w1[c] + av.z * w2[c] + av.w * w3[c];
    }
    __syncthreads();
    #pragma unroll
    for (int c = 0; c < 32; c += 4)
        *(float4*)&a_lds[lane * 132 + co + c] = make_float4(acc[c], acc[c+1], acc[c+2], acc[c+3]);
    __syncthreads();
    const int q4 = lane31 << 2;
    #pragma unroll
    for (int p = 0; p < 8; ++p) {
        const int ln = wv * 16 + p * 2 + half;
        const int n  = base + ln;
        if (n < N_NODES)
            *(float4*)&out[(size_t)n * 128 + q4] = *(const float4*)&a_lds[ln * 132 + q4];
    }
}

// ================= fallback (proven R3 atomic path) =================
__global__ void scale_kernel(const int* __restrict__ cnt_j, const int* __restrict__ cnt_k,
                             float* __restrict__ scale_j, float* __restrict__ scale_k) {
    int n = blockIdx.x * blockDim.x + threadIdx.x;
    if (n < N_NODES) {
        scale_j[n] = 0.5f / (float)max(cnt_j[n], 1);
        scale_k[n] = 0.5f / (float)max(cnt_k[n], 1);
    }
}

__global__ __launch_bounds__(256, 3) void mlp_mfma_atomic(
    const unsigned short* __restrict__ xb, const int* __restrict__ qidx,
    const float* __restrict__ attr,
    const float* __restrict__ W1, const float* __restrict__ b1,
    const float* __restrict__ b2, const float* __restrict__ b3,
    const unsigned short* __restrict__ W1f, const unsigned short* __restrict__ W2f,
    const unsigned short* __restrict__ W3f,
    const float* __restrict__ scale_j, const float* __restrict__ scale_k,
    float* __restrict__ aggr)
{
    __shared__ __align__(16) unsigned short hbuf[4][4096];
    const int tid  = threadIdx.x;
    const int lane = tid & 63;
    const int wv   = tid >> 6;
    const int g    = blockIdx.x * 4 + wv;
    if (g >= NWAVES) return;
    const int D0   = g * 32;
    const int m16  = lane & 15;
    const int quad = lane >> 4;
    unsigned short* hs = hbuf[wv];

    int irow[2], lrow[2];
    irow[0] = qidx[D0 + m16];
    irow[1] = qidx[D0 + 16 + m16];
    lrow[0] = qidx[3 * N_DIH + D0 + m16];
    lrow[1] = qidx[3 * N_DIH + D0 + 16 + m16];

    v4f acc[2][4];
    #pragma unroll
    for (int mt = 0; mt < 2; ++mt)
        #pragma unroll
        for (int nt = 0; nt < 4; ++nt) acc[mt][nt] = (v4f){0.f, 0.f, 0.f, 0.f};
    #pragma unroll
    for (int kc = 0; kc < 8; ++kc) {
        const int side = kc >> 2;
        const int coff = (kc & 3) * 32 + quad * 8;
        const int r0 = side ? lrow[0] : irow[0];
        const int r1 = side ? lrow[1] : irow[1];
        const v8s a0 = *(const v8s*)(xb + (size_t)r0 * 128 + coff);
        const v8s a1 = *(const v8s*)(xb + (size_t)r1 * 128 + coff);
        #pragma unroll
        for (int nt = 0; nt < 4; ++nt) {
            const v8s b = *(const v8s*)(W1f + ((kc * 4 + nt) * 64 + lane) * 8);
            acc[0][nt] = __builtin_amdgcn_mfma_f32_16x16x32_bf16(a0, b, acc[0][nt], 0, 0, 0);
            acc[1][nt] = __builtin_amdgcn_mfma_f32_16x16x32_bf16(a1, b, acc[1][nt], 0, 0, 0);
        }
    }
    #pragma unroll
    for (int mt = 0; mt < 2; ++mt) {
        #pragma unroll
        for (int nt = 0; nt < 4; ++nt) {
            const int c = nt * 16 + m16;
            const float b1c = b1[c];
            const float wa0 = W1[256 * 64 + c];
            const float wa1 = W1[257 * 64 + c];
            const float wa2 = W1[258 * 64 + c];
            const int quadp = (nt * 2 + (m16 >> 3)) & 3;
            const int jp    = m16 & 7;
            const int kc2   = nt >> 1;
            #pragma unroll
            for (int reg = 0; reg < 4; ++reg) {
                const int r = quad * 4 + reg;
                const int d = D0 + mt * 16 + r;
                float v = acc[mt][nt][reg] + b1c
                        + attr[(size_t)d * 3 + 0] * wa0
                        + attr[(size_t)d * 3 + 1] * wa1
                        + attr[(size_t)d * 3 + 2] * wa2;
                v = silu(v);
                hs[mt * 1024 + kc2 * 512 + (r + 16 * quadp) * 8 + jp] = bf16_rne(v);
            }
        }
    }
    v4f acc2[2][4];
    #pragma unroll
    for (int mt = 0; mt < 2; ++mt)
        #pragma unroll
        for (int nt = 0; nt < 4; ++nt) acc2[mt][nt] = (v4f){0.f, 0.f, 0.f, 0.f};
    #pragma unroll
    for (int kc = 0; kc < 2; ++kc) {
        const v8s a0 = *(const v8s*)(hs +        kc * 512 + lane * 8);
        const v8s a1 = *(const v8s*)(hs + 1024 + kc * 512 + lane * 8);
        #pragma unroll
        for (int nt = 0; nt < 4; ++nt) {
            const v8s b = *(const v8s*)(W2f + ((kc * 4 + nt) * 64 + lane) * 8);
            acc2[0][nt] = __builtin_amdgcn_mfma_f32_16x16x32_bf16(a0, b, acc2[0][nt], 0, 0, 0);
            acc2[1][nt] = __builtin_amdgcn_mfma_f32_16x16x32_bf16(a1, b, acc2[1][nt], 0, 0, 0);
        }
    }
    #pragma unroll
    for (int mt = 0; mt < 2; ++mt) {
        #pragma unroll
        for (int nt = 0; nt < 4; ++nt) {
            const float b2c = b2[nt * 16 + m16];
            const int quadp = (nt * 2 + (m16 >> 3)) & 3;
            const int jp    = m16 & 7;
            const int kc2   = nt >> 1;
            #pragma unroll
            for (int reg = 0; reg < 4; ++reg) {
                const int r = quad * 4 + reg;
                const float v = silu(acc2[mt][nt][reg] + b2c);
                hs[2048 + mt * 1024 + kc2 * 512 + (r + 16 * quadp) * 8 + jp] = bf16_rne(v);
            }
        }
    }
    v4f acc3[2][8];
    #pragma unroll
    for (int mt = 0; mt < 2; ++mt)
        #pragma unroll
        for (int nt = 0; nt < 8; ++nt) acc3[mt][nt] = (v4f){0.f, 0.f, 0.f, 0.f};
    #pragma unroll
    for (int kc = 0; kc < 2; ++kc) {
        const v8s a0 = *(const v8s*)(hs + 2048 +        kc * 512 + lane * 8);
        const v8s a1 = *(const v8s*)(hs + 2048 + 1024 + kc * 512 + lane * 8);
        #pragma unroll
        for (int nt = 0; nt < 8; ++nt) {
            const v8s b = *(const v8s*)(W3f + ((kc * 8 + nt) * 64 + lane) * 8);
            acc3[0][nt] = __builtin_amdgcn_mfma_f32_16x16x32_bf16(a0, b, acc3[0][nt], 0, 0, 0);
            acc3[1][nt] = __builtin_amdgcn_mfma_f32_16x16x32_bf16(a1, b, acc3[1][nt], 0, 0, 0);
        }
    }
    #pragma unroll
    for (int mt = 0; mt < 2; ++mt) {
        int jn[4], kn[4]; float sjv[4], skv[4];
        #pragma unroll
        for (int reg = 0; reg < 4; ++reg) {
            const int d = D0 + mt * 16 + quad * 4 + reg;
            jn[reg] = qidx[N_DIH + d];
            kn[reg] = qidx[2 * N_DIH + d];
            sjv[reg] = scale_j[jn[reg]];
            skv[reg] = scale_k[kn[reg]];
        }
        #pragma unroll
        for (int nt = 0; nt < 8; ++nt) {
            const int c = nt * 16 + m16;
            const float b3c = b3[c];
            #pragma unroll
            for (int reg = 0; reg < 4; ++reg) {
                const float v = acc3[mt][nt][reg] + b3c;
                atomicAdd(&aggr[(size_t)jn[reg] * 128 + c], v * sjv[reg]);
                atomicAdd(&aggr[(size_t)kn[reg] * 128 + c], v * skv[reg]);
            }
        }
    }
}

#define OB    256
#define OTILE 64
__global__ __launch_bounds__(OB, 2) void out_kernel(const float* __restrict__ aggr,
                                                    const float* __restrict__ Wout,
                                                    float* __restrict__ out) {
    __shared__ float a_lds[OTILE * 132];
    const int tid  = threadIdx.x;
    const int lane = tid & 63;
    const int wv   = __builtin_amdgcn_readfirstlane(tid >> 6);
    const int base = blockIdx.x * OTILE;
    const int half = lane >> 5;
    const int q4   = (lane & 31) << 2;
    #pragma unroll
    for (int p = 0; p < 8; ++p) {
        const int ln = wv * 16 + p * 2 + half;
        const int n  = base + ln;
        float4 v = make_float4(0.f, 0.f, 0.f, 0.f);
        if (n < N_NODES) v = *(const float4*)&aggr[(size_t)n * 128 + q4];
        *(float4*)&a_lds[ln * 132 + q4] = v;
    }
    __syncthreads();
    const int c0 = wv * 32;
    float acc[32];
    #pragma unroll
    for (int c = 0; c < 32; ++c) acc[c] = 0.0f;
    const float* ap = &a_lds[lane * 132];
    #pragma unroll 2
    for (int d = 0; d < 128; d += 4) {
        const float4 av = *(const float4*)&ap[d];
        const float* w0 = &Wout[(d + 0) * 128 + c0];
        const float* w1 = &Wout[(d + 1) * 128 + c0];
        const float* w2 = &Wout[(d + 2) * 128 + c0];
        const float* w3 = &Wout[(d + 3) * 128 + c0];
        #pragma unroll
        for (int c = 0; c < 32; ++c)
            acc[c] += av.x * w0[c] + av.y * w1[c] + av.z * w2[c] + av.w * w3[c];
    }
    __syncthreads();
    #pragma unroll
    for (int c = 0; c < 32; c += 4)
        *(float4*)&a_lds[lane * 132 + c0 + c] = make_float4(acc[c], acc[c+1], acc[c+2], acc[c+3]);
    __syncthreads();
    #pragma unroll
    for (int p = 0; p < 8; ++p) {
        const int ln = wv * 16 + p * 2 + half;
        const int n  = base + ln;
        if (n < N_NODES)
            *(float4*)&out[(size_t)n * 128 + q4] = *(const float4*)&a_lds[ln * 132 + q4];
    }
}

extern "C" void kernel_launch(void* const* d_in, const int* in_sizes, int n_in,
                              void* d_out, int out_size, void* d_ws, size_t ws_size,
                              hipStream_t stream) {
    const float* x    = (const float*)d_in[0];
    const int*   qidx = (const int*)d_in[1];
    const float* attr = (const float*)d_in[2];
    const float* W1   = (const float*)d_in[3];
    const float* b1   = (const float*)d_in[4];
    const float* W2   = (const float*)d_in[5];
    const float* b2   = (const float*)d_in[6];
    const float* W3   = (const float*)d_in[7];
    const float* b3   = (const float*)d_in[8];
    const float* Wout = (const float*)d_in[9];
    float* out = (float*)d_out;
    float* wsf = (float*)d_ws;

    const size_t words = ws_size / 4;
    if (words >= (size_t)79300000) {
        // ---- tier A': scatter-on-write path (316.9 MB; inert on smaller ws) ----
        size_t o = 0;
        unsigned short* h2j = (unsigned short*)wsf;          o += 32000000;
        unsigned short* h2k = (unsigned short*)(wsf + o);    o += 32000000;
        _Float16* uvp = (_Float16*)(wsf + o);                o += 12800000;  // f16: half used
        unsigned short* W1f = (unsigned short*)(wsf + o);    o += 8192;
        unsigned short* W2f = (unsigned short*)(wsf + o);    o += 2048;
        unsigned short* W3f = (unsigned short*)(wsf + o);    o += 4096;
        unsigned short* W1g = (unsigned short*)(wsf + o);    o += 8192;
        float* W34  = wsf + o;                               o += 8192;
        float* b34  = wsf + o;                               o += 128;
        float* PK   = wsf + o;                               o += 256;
        int* cnt_j  = (int*)(wsf + o);                       o += 100000;
        int* cnt_k  = (int*)(wsf + o);                       o += 100000;
        int* off_j  = (int*)(wsf + o);                       o += 100001;
        int* off_k  = (int*)(wsf + o);                       o += 100001;
        int* rank_j = (int*)(wsf + o);                       o += 1000000;
        int* rank_k = (int*)(wsf + o);                       o += 1000000;

        hipMemsetAsync(cnt_j, 0, (size_t)200000 * sizeof(int), stream);
        prep_kernel<<<PREP_MAIN, 256, 0, stream>>>(
            x, h2j /*xb unused*/, W1, W2, W3, b1, b3, Wout,
            W1f, W2f, W3f, W1g, W34, b34, PK, qidx, cnt_j, cnt_k, rank_j, rank_k);
        scan_kernel<<<2, 1024, 0, stream>>>(cnt_j, cnt_k, off_j, off_k);
        uv_kernel<<<(UVW + 3) / 4, 256, 0, stream>>>(x, W1g, uvp);
        mlp2s_kernel<<<NW16 / 4, 256, 0, stream>>>(
            uvp, qidx, attr, PK, W2f, b2, off_j, off_k, rank_j, rank_k, h2j, h2k);
        aggregate_seq<<<(N_NODES + 63) / 64, 256, 0, stream>>>(
            h2j, h2k, off_j, off_k, W34, b34, out);
    } else if (words >= (size_t)47500000) {
        // ---- tier A: uv-precompute + perm-gather path (ACTIVE on this ws) ----
        size_t o = 0;
        unsigned short* h2  = (unsigned short*)wsf;          o += 32000000;
        _Float16* uvp = (_Float16*)(wsf + o);                o += 12800000;  // f16: half used
        unsigned short* W1f = (unsigned short*)(wsf + o);    o += 8192;
        unsigned short* W2f = (unsigned short*)(wsf + o);    o += 2048;
        unsigned short* W3f = (unsigned short*)(wsf + o);    o += 4096;
        unsigned short* W1g = (unsigned short*)(wsf + o);    o += 8192;
        float* W34  = wsf + o;                               o += 8192;
        float* b34  = wsf + o;                               o += 128;
        float* PK   = wsf + o;                               o += 256;
        int* cnt_j  = (int*)(wsf + o);                       o += 100000;
        int* cnt_k  = (int*)(wsf + o);                       o += 100000;
        int* off_j  = (int*)(wsf + o);                       o += 100001;
        int* off_k  = (int*)(wsf + o);                       o += 100001;
        int* perm_j = (int*)(wsf + o);                       o += 1000000;
        int* perm_k = (int*)(wsf + o);                       o += 1000000;
        int* rank_j = (int*)h2;
        int* rank_k = rank_j + N_DIH;

        hipMemsetAsync(cnt_j, 0, (size_t)200000 * sizeof(int), stream);
        prep_kernel<<<PREP_MAIN, 256, 0, stream>>>(
            x, h2 /*xb unused*/, W1, W2, W3, b1, b3, Wout,
            W1f, W2f, W3f, W1g, W34, b34, PK, qidx, cnt_j, cnt_k, rank_j, rank_k);
        scan_kernel<<<2, 1024, 0, stream>>>(cnt_j, cnt_k, off_j, off_k);
        permute_kernel<<<(N_DIH + 255) / 256, 256, 0, stream>>>(
            qidx, off_j, off_k, rank_j, rank_k, perm_j, perm_k);
        uv_kernel<<<(UVW + 3) / 4, 256, 0, stream>>>(x, W1g, uvp);
        mlp2_kernel<<<NW16 / 4, 256, 0, stream>>>(uvp, qidx, attr, PK, W2f, b2, h2);
        aggregate_out64<<<(N_NODES + 63) / 64, 256, 0, stream>>>(
            h2, off_j, off_k, perm_j, perm_k, W34, b34, out);
    } else if (words >= (size_t)41100000) {
        // ---- tier B: round-1 path ----
        size_t o = 0;
        unsigned short* h2  = (unsigned short*)wsf;          o += 32000000;
        unsigned short* xb  = (unsigned short*)(wsf + o);    o += 6400000;
        unsigned short* W1f = (unsigned short*)(wsf + o);    o += 8192;
        unsigned short* W2f = (unsigned short*)(wsf + o);    o += 2048;
        unsigned short* W3f = (unsigned short*)(wsf + o);    o += 4096;
        float* W34  = wsf + o;                               o += 8192;
        float* b34  = wsf + o;                               o += 128;
        int* cnt_j  = (int*)(wsf + o);                       o += 100000;
        int* cnt_k  = (int*)(wsf + o);                       o += 100000;
        int* off_j  = (int*)(wsf + o);                       o += 100001;
        int* off_k  = (int*)(wsf + o);                       o += 100001;
        int* perm_j = (int*)(wsf + o);                       o += 1000000;
        int* perm_k = (int*)(wsf + o);                       o += 1000000;
        unsigned short* W1g = (unsigned short*)(wsf + o);    o += 8192;
        float* PK   = wsf + o;                               o += 256;
        int* rank_j = (int*)h2;
        int* rank_k = rank_j + N_DIH;

        hipMemsetAsync(cnt_j, 0, (size_t)200000 * sizeof(int), stream);
        prep_kernel<<<PREP_ALL, 256, 0, stream>>>(
            x, xb, W1, W2, W3, b1, b3, Wout,
            W1f, W2f, W3f, W1g, W34, b34, PK, qidx, cnt_j, cnt_k, rank_j, rank_k);
        scan_kernel<<<2, 1024, 0, stream>>>(cnt_j, cnt_k, off_j, off_k);
        permute_kernel<<<(N_DIH + 255) / 256, 256, 0, stream>>>(
            qidx, off_j, off_k, rank_j, rank_k, perm_j, perm_k);
        mlp12_kernel<<<NW16 / 4, 256, 0, stream>>>(
            xb, qidx, attr, W1, b1, b2, W1f, W2f, h2);
        aggregate_out64<<<(N_NODES + 63) / 64, 256, 0, stream>>>(
            h2, off_j, off_k, perm_j, perm_k, W34, b34, out);
    } else {
        // ---- tier C: proven atomic fallback (78.5 MB) ----
        int*   cnt_j   = (int*)wsf;
        int*   cnt_k   = cnt_j + N_NODES;
        float* scale_j = wsf + 200000;
        float* scale_k = wsf + 300000;
        float* aggr    = wsf + 400000;
        unsigned short* xb  = (unsigned short*)(wsf + 13200000);
        unsigned short* W1f = (unsigned short*)(wsf + 19600000);
        unsigned short* W2f = (unsigned short*)(wsf + 19608192);
        unsigned short* W3f = (unsigned short*)(wsf + 19610240);
        float* W34 = wsf + 19612288;   // scratch (unused result ok)
        float* b34 = wsf + 19612288;   // overlap fine for fallback
        unsigned short* W1g = (unsigned short*)(wsf + 19612288); // scratch overlap
        float* PK  = wsf + 19612288;   // scratch overlap

        hipMemsetAsync(cnt_j, 0, (size_t)2 * N_NODES * sizeof(int), stream);
        hipMemsetAsync(aggr, 0, (size_t)N_NODES * 128 * sizeof(float), stream);
        prep_kernel<<<PREP_ALL, 256, 0, stream>>>(
            x, xb, W1, W2, W3, b1, b3, Wout,
            W1f, W2f, W3f, W1g, W34, b34, PK, qidx, cnt_j, cnt_k, nullptr, nullptr);
        scale_kernel<<<(N_NODES + 255) / 256, 256, 0, stream>>>(cnt_j, cnt_k, scale_j, scale_k);
        mlp_mfma_atomic<<<(NWAVES + 3) / 4, 256, 0, stream>>>(
            xb, qidx, attr, W1, b1, b2, b3, W1f, W2f, W3f, scale_j, scale_k, aggr);
        out_kernel<<<(N_NODES + OTILE - 1) / OTILE, OB, 0, stream>>>(aggr, Wout, out);
    }
}

// Round 10
// 516.676 us; speedup vs baseline: 1.1751x; 1.0380x over previous
//
#include <hip/hip_runtime.h>

#define N_NODES    100000
#define N_DIH      1000000
#define SCALAR_DIM 128
#define HIDDEN     64
#define ATTR_DIM   3

typedef short v8s __attribute__((ext_vector_type(8)));
typedef float v4f __attribute__((ext_vector_type(4)));
typedef _Float16 v8h __attribute__((ext_vector_type(8)));

__device__ __forceinline__ float silu(float v) {
    return __fdividef(v, 1.0f + __expf(-v));
}

__device__ __forceinline__ unsigned short bf16_rne(float f) {
    unsigned int u = __float_as_uint(f);
    u = (u + 0x7FFFu + ((u >> 16) & 1u)) >> 16;
    return (unsigned short)u;
}

__device__ __forceinline__ float2 bf2_to_f2(unsigned int v) {
    float2 r;
    r.x = __uint_as_float(v << 16);
    r.y = __uint_as_float(v & 0xffff0000u);
    return r;
}

// ---------------- prep ----------------
#define PREP_W   112
#define PREP_W34 33
#define PREP_G   64
#define PREP_H   3907
#define PREP_XB  12500
#define PREP_MAIN (PREP_W + PREP_W34 + PREP_G + PREP_H)
#define PREP_ALL  (PREP_MAIN + PREP_XB)

__global__ void prep_kernel(const float* __restrict__ x, unsigned short* __restrict__ xb,
                            const float* __restrict__ W1, const float* __restrict__ W2,
                            const float* __restrict__ W3, const float* __restrict__ b1,
                            const float* __restrict__ b3,
                            const float* __restrict__ Wout,
                            unsigned short* __restrict__ W1f, unsigned short* __restrict__ W2f,
                            unsigned short* __restrict__ W3f, unsigned short* __restrict__ W1g,
                            float* __restrict__ W34, float* __restrict__ b34,
                            float* __restrict__ PK,
                            const int* __restrict__ qidx,
                            int* __restrict__ cnt_j, int* __restrict__ cnt_k,
                            int* __restrict__ rank_j, int* __restrict__ rank_k) {
    const int b = blockIdx.x;
    if (b < PREP_W) {
        const int tid = b * 256 + threadIdx.x;
        if (tid < 16384) {                     // W1f: kc<8, nt<4
            const int j = tid & 7, lane = (tid >> 3) & 63, t = tid >> 9;
            const int k = (t >> 2) * 32 + ((lane >> 4) << 3) + j;
            const int n = (t & 3) * 16 + (lane & 15);
            W1f[tid] = bf16_rne(W1[k * 64 + n]);
        } else if (tid < 20480) {              // W2f: kc<2, nt<4
            const int i = tid - 16384;
            const int j = i & 7, lane = (i >> 3) & 63, t = i >> 9;
            const int k = (t >> 2) * 32 + ((lane >> 4) << 3) + j;
            const int n = (t & 3) * 16 + (lane & 15);
            W2f[i] = bf16_rne(W2[k * 64 + n]);
        } else if (tid < 28672) {              // W3f (fallback path only)
            const int i = tid - 20480;
            const int j = i & 7, lane = (i >> 3) & 63, t = i >> 9;
            const int k = (t >> 3) * 32 + ((lane >> 4) << 3) + j;
            const int n = (t & 7) * 16 + (lane & 15);
            W3f[i] = bf16_rne(W3[k * 128 + n]);
        }
    } else if (b < PREP_W + PREP_W34) {
        const int t34 = (b - PREP_W) * 256 + threadIdx.x;
        if (t34 < 8192) {                      // W34[r][c] = sum_m W3[r][m]*Wout[m][c]
            const int r = t34 >> 7, c = t34 & 127;
            float s = 0.f;
            #pragma unroll 4
            for (int m = 0; m < 128; ++m) s += W3[r * 128 + m] * Wout[m * 128 + c];
            W34[t34] = s;
        } else if (t34 < 8320) {               // b34[c] = sum_m b3[m]*Wout[m][c]
            const int c = t34 - 8192;
            float s = 0.f;
            #pragma unroll 4
            for (int m = 0; m < 128; ++m) s += b3[m] * Wout[m * 128 + c];
            b34[c] = s;
        } else if (t34 < 8384) {               // PK[c] = {wa0, wa1, wa2, b1}
            const int c = t34 - 8320;
            PK[c * 4 + 0] = W1[256 * 64 + c];
            PK[c * 4 + 1] = W1[257 * 64 + c];
            PK[c * 4 + 2] = W1[258 * 64 + c];
            PK[c * 4 + 3] = b1[c];
        }
    } else if (b < PREP_W + PREP_W34 + PREP_G) {
        // W1g: B-frag pack of W' (128x128), W'[k][n] = n<64 ? W1a[k][n] : W1b[k][n-64]
        const int i = (b - PREP_W - PREP_W34) * 256 + threadIdx.x;   // < 16384
        const int j = i & 7, lane = (i >> 3) & 63, t = i >> 9;       // t < 32
        const int k = (t >> 3) * 32 + ((lane >> 4) << 3) + j;        // k < 128
        const int n = (t & 7) * 16 + (lane & 15);                    // n < 128
        const float w = (n < 64) ? W1[k * 64 + n] : W1[(128 + k) * 64 + (n - 64)];
        W1g[i] = bf16_rne(w);
    } else if (b < PREP_MAIN) {
        const int t = (b - PREP_W - PREP_W34 - PREP_G) * 256 + threadIdx.x;
        if (t < N_DIH) {
            const int rj = atomicAdd(&cnt_j[qidx[N_DIH + t]], 1);
            const int rk = atomicAdd(&cnt_k[qidx[2 * N_DIH + t]], 1);
            if (rank_j != nullptr) {           // uniform branch; fallback passes null
                rank_j[t] = rj;
                rank_k[t] = rk;
            }
        }
    } else {
        const int t = (b - PREP_MAIN) * 256 + threadIdx.x;           // < 3.2M
        const float4 v = *(const float4*)&x[(size_t)t * 4];
        ushort4 o;
        o.x = bf16_rne(v.x); o.y = bf16_rne(v.y); o.z = bf16_rne(v.z); o.w = bf16_rne(v.w);
        *(ushort4*)&xb[(size_t)t * 4] = o;
    }
}

// ---------------- scan: exclusive prefix over counts -> off ----------------
__global__ __launch_bounds__(1024) void scan_kernel(const int* __restrict__ cnt_j,
                                                    const int* __restrict__ cnt_k,
                                                    int* __restrict__ off_j, int* __restrict__ off_k) {
    const int* cnt = blockIdx.x ? cnt_k : cnt_j;
    int* off = blockIdx.x ? off_k : off_j;
    __shared__ int wtot[17];
    const int tid = threadIdx.x, lane = tid & 63, wv = tid >> 6;
    int carry = 0;
    for (int base = 0; base < N_NODES; base += 1024) {
        const int i = base + tid;
        const int v = (i < N_NODES) ? cnt[i] : 0;
        int inc = v;
        #pragma unroll
        for (int o = 1; o < 64; o <<= 1) {
            const int t = __shfl_up(inc, o);
            if (lane >= o) inc += t;
        }
        if (lane == 63) wtot[wv] = inc;
        __syncthreads();
        if (tid == 0) {
            int run = 0;
            #pragma unroll
            for (int w = 0; w < 16; ++w) { const int t = wtot[w]; wtot[w] = run; run += t; }
            wtot[16] = run;
        }
        __syncthreads();
        const int excl = inc - v + wtot[wv] + carry;
        if (i < N_NODES) off[i] = excl;
        carry += wtot[16];
        __syncthreads();
    }
    if (tid == 0) off[N_NODES] = carry;
}

// ---------------- permute (tier B): atomic-free scatter using captured ranks ----------------
__global__ void permute_kernel(const int* __restrict__ qidx,
                               const int* __restrict__ off_j, const int* __restrict__ off_k,
                               const int* __restrict__ rank_j, const int* __restrict__ rank_k,
                               int* __restrict__ perm_j, int* __restrict__ perm_k) {
    const int t = blockIdx.x * blockDim.x + threadIdx.x;
    if (t < N_DIH) {
        const int j = qidx[N_DIH + t];
        perm_j[off_j[j] + rank_j[t]] = t;
        const int k = qidx[2 * N_DIH + t];
        perm_k[off_k[k] + rank_k[t]] = t;
    }
}

// ---------------- permute2 (tier A): k-sorted slot -> j-sorted row position ----------------
// permk2[off_k[k[d]] + rank_k[d]] = off_j[j[d]] + rank_j[d]   (composed index: the
// k-aggregation gathers h2j rows directly, no second sorted copy needed)
__global__ void permute2_kernel(const int* __restrict__ qidx,
                                const int* __restrict__ off_j, const int* __restrict__ off_k,
                                const int* __restrict__ rank_j, const int* __restrict__ rank_k,
                                int* __restrict__ permk2) {
    const int t = blockIdx.x * blockDim.x + threadIdx.x;
    if (t < N_DIH) {
        const int j = qidx[N_DIH + t];
        const int k = qidx[2 * N_DIH + t];
        permk2[off_k[k] + rank_k[t]] = off_j[j] + rank_j[t];
    }
}

// ========== uv: per-node partials U = x@W1a, V = x@W1b (f16, row = [U|V]) ==========
#define UVW 3125    // 100000 / 32 rows per wave

__global__ __launch_bounds__(256, 4) void uv_kernel(
    const float* __restrict__ x, const unsigned short* __restrict__ W1g,
    _Float16* __restrict__ uv)
{
    const int tid = threadIdx.x, lane = tid & 63, wv = tid >> 6;
    const int g = blockIdx.x * 4 + wv;
    if (g >= UVW) return;
    const int D0 = g * 32;
    const int m16 = lane & 15, quad = lane >> 4;
    const int r0 = D0 + m16, r1 = D0 + 16 + m16;

    v4f acc[2][8];
    #pragma unroll
    for (int mt = 0; mt < 2; ++mt)
        #pragma unroll
        for (int nt = 0; nt < 8; ++nt) acc[mt][nt] = (v4f){0.f, 0.f, 0.f, 0.f};

    #pragma unroll
    for (int kc = 0; kc < 4; ++kc) {
        const int co = kc * 32 + quad * 8;
        v8s a0, a1;
        {
            const float4 f0 = *(const float4*)&x[(size_t)r0 * 128 + co];
            const float4 f1 = *(const float4*)&x[(size_t)r0 * 128 + co + 4];
            a0[0] = (short)bf16_rne(f0.x); a0[1] = (short)bf16_rne(f0.y);
            a0[2] = (short)bf16_rne(f0.z); a0[3] = (short)bf16_rne(f0.w);
            a0[4] = (short)bf16_rne(f1.x); a0[5] = (short)bf16_rne(f1.y);
            a0[6] = (short)bf16_rne(f1.z); a0[7] = (short)bf16_rne(f1.w);
        }
        {
            const float4 f0 = *(const float4*)&x[(size_t)r1 * 128 + co];
            const float4 f1 = *(const float4*)&x[(size_t)r1 * 128 + co + 4];
            a1[0] = (short)bf16_rne(f0.x); a1[1] = (short)bf16_rne(f0.y);
            a1[2] = (short)bf16_rne(f0.z); a1[3] = (short)bf16_rne(f0.w);
            a1[4] = (short)bf16_rne(f1.x); a1[5] = (short)bf16_rne(f1.y);
            a1[6] = (short)bf16_rne(f1.z); a1[7] = (short)bf16_rne(f1.w);
        }
        #pragma unroll
        for (int nt = 0; nt < 8; ++nt) {
            const v8s bf = *(const v8s*)(W1g + ((kc * 8 + nt) * 64 + lane) * 8);
            acc[0][nt] = __builtin_amdgcn_mfma_f32_16x16x32_bf16(a0, bf, acc[0][nt], 0, 0, 0);
            acc[1][nt] = __builtin_amdgcn_mfma_f32_16x16x32_bf16(a1, bf, acc[1][nt], 0, 0, 0);
        }
    }
    #pragma unroll
    for (int mt = 0; mt < 2; ++mt)
        #pragma unroll
        for (int nt = 0; nt < 8; ++nt) {
            const int c = nt * 16 + m16;
            #pragma unroll
            for (int reg = 0; reg < 4; ++reg) {
                const int n = D0 + mt * 16 + quad * 4 + reg;
                uv[(size_t)n * 128 + c] = (_Float16)acc[mt][nt][reg];
            }
        }
}

#define NW16 62500   // 1e6 / 16 dihedrals per wave

// ========== mlp2j (tier A): gather f16 uv, layer-1 finish, layer-2 MFMA,
// scatter rows directly into j-sorted h2j (slots bijective -> no conflicts) ==========
__global__ __launch_bounds__(256, 8) void mlp2j_kernel(
    const _Float16* __restrict__ uv, const int* __restrict__ qidx,
    const float* __restrict__ attr, const float* __restrict__ PK,
    const unsigned short* __restrict__ W2f, const float* __restrict__ b2,
    const int* __restrict__ off_j, const int* __restrict__ rank_j,
    unsigned short* __restrict__ h2j)
{
    __shared__ __align__(16) unsigned short hbuf[4][1024];   // per wave: row staging
    const int tid = threadIdx.x, lane = tid & 63, wv = tid >> 6;
    const int g = blockIdx.x * 4 + wv;                       // grid exact: no guard
    const int D0 = g * 16;
    const int m16 = lane & 15, quad = lane >> 4;
    unsigned short* hs = hbuf[wv];

    const int d = D0 + m16;
    const int irow = qidx[d];
    const int lrow = qidx[3 * N_DIH + d];
    const int jn = qidx[N_DIH + d];
    const int pj = off_j[jn] + rank_j[d];      // destination row in h2j

    const _Float16* up = uv + (size_t)irow * 128 + quad * 8;       // U part: cols [0,64)
    const _Float16* vp = uv + (size_t)lrow * 128 + 64 + quad * 8;  // V part: cols [64,128)
    const v8h u0 = *(const v8h*)(up + 0);
    const v8h u1 = *(const v8h*)(up + 32);
    const v8h w0 = *(const v8h*)(vp + 0);
    const v8h w1 = *(const v8h*)(vp + 32);
    const float a0 = attr[(size_t)d * 3 + 0];
    const float a1 = attr[(size_t)d * 3 + 1];
    const float a2 = attr[(size_t)d * 3 + 2];

    const int cb = quad * 8;
    v8s af0, af1;
    #pragma unroll
    for (int e = 0; e < 8; ++e) {
        const float4 pk0 = *(const float4*)&PK[(size_t)(cb + e) * 4];
        const float s0 = (float)u0[e] + (float)w0[e] + pk0.x * a0 + pk0.y * a1 + pk0.z * a2 + pk0.w;
        af0[e] = (short)bf16_rne(silu(s0));
        const float4 pk1 = *(const float4*)&PK[(size_t)(32 + cb + e) * 4];
        const float s1 = (float)u1[e] + (float)w1[e] + pk1.x * a0 + pk1.y * a1 + pk1.z * a2 + pk1.w;
        af1[e] = (short)bf16_rne(silu(s1));
    }

    v4f acc2[4];
    #pragma unroll
    for (int nt = 0; nt < 4; ++nt) acc2[nt] = (v4f){0.f, 0.f, 0.f, 0.f};
    #pragma unroll
    for (int nt = 0; nt < 4; ++nt) {
        const v8s bA = *(const v8s*)(W2f + ((nt) * 64 + lane) * 8);
        const v8s bB = *(const v8s*)(W2f + ((4 + nt) * 64 + lane) * 8);
        acc2[nt] = __builtin_amdgcn_mfma_f32_16x16x32_bf16(af0, bA, acc2[nt], 0, 0, 0);
        acc2[nt] = __builtin_amdgcn_mfma_f32_16x16x32_bf16(af1, bB, acc2[nt], 0, 0, 0);
    }

    // epilogue: silu -> bf16 rows [row][c] in LDS, then per-row scatter to h2j[pj]
    // (8 lanes x 16B = one 128B row per group; same-wave DS in-order -> safe)
    #pragma unroll
    for (int nt = 0; nt < 4; ++nt) {
        const int c = nt * 16 + m16;
        const float b2c = b2[c];
        #pragma unroll
        for (int reg = 0; reg < 4; ++reg) {
            const int row = quad * 4 + reg;
            hs[row * 64 + c] = bf16_rne(silu(acc2[nt][reg] + b2c));
        }
    }
    const int sub = lane & 7;
    #pragma unroll
    for (int i = 0; i < 2; ++i) {
        const int row = i * 8 + (lane >> 3);
        const int pjr = __shfl(pj, row);
        const v8s rowv = *(const v8s*)(hs + i * 512 + lane * 8);
        *(v8s*)(h2j + (size_t)pjr * 64 + sub * 8) = rowv;
    }
}

// ========== tier-B MLP (kept verbatim for smaller workspaces) ==========
#define NWAVES 31250    // 1e6 / 32

__global__ __launch_bounds__(256, 8) void mlp12_kernel(
    const unsigned short* __restrict__ xb, const int* __restrict__ qidx,
    const float* __restrict__ attr,
    const float* __restrict__ W1, const float* __restrict__ b1,
    const float* __restrict__ b2,
    const unsigned short* __restrict__ W1f, const unsigned short* __restrict__ W2f,
    unsigned short* __restrict__ h2)
{
    __shared__ __align__(16) unsigned short hbuf[4][1024];
    const int tid  = threadIdx.x;
    const int lane = tid & 63;
    const int wv   = tid >> 6;
    const int g    = blockIdx.x * 4 + wv;
    const int D0   = g * 16;
    const int m16  = lane & 15;
    const int quad = lane >> 4;
    unsigned short* hs = hbuf[wv];

    const int irow = qidx[D0 + m16];
    const int lrow = qidx[3 * N_DIH + D0 + m16];

    v4f acc[4];
    #pragma unroll
    for (int nt = 0; nt < 4; ++nt) acc[nt] = (v4f){0.f, 0.f, 0.f, 0.f};

    #pragma unroll
    for (int kc = 0; kc < 8; ++kc) {
        const int side = kc >> 2;
        const int coff = (kc & 3) * 32 + quad * 8;
        const int r0 = side ? lrow : irow;
        const v8s a0 = *(const v8s*)(xb + (size_t)r0 * 128 + coff);
        #pragma unroll
        for (int nt = 0; nt < 4; ++nt) {
            const v8s b = *(const v8s*)(W1f + ((kc * 4 + nt) * 64 + lane) * 8);
            acc[nt] = __builtin_amdgcn_mfma_f32_16x16x32_bf16(a0, b, acc[nt], 0, 0, 0);
        }
    }

    #pragma unroll
    for (int nt = 0; nt < 4; ++nt) {
        const int c = nt * 16 + m16;
        const float b1c = b1[c];
        const float wa0 = W1[256 * 64 + c];
        const float wa1 = W1[257 * 64 + c];
        const float wa2 = W1[258 * 64 + c];
        const int quadp = (nt * 2 + (m16 >> 3)) & 3;
        const int jp    = m16 & 7;
        const int kc2   = nt >> 1;
        #pragma unroll
        for (int reg = 0; reg < 4; ++reg) {
            const int r = quad * 4 + reg;
            const int d = D0 + r;
            float v = acc[nt][reg] + b1c
                    + attr[(size_t)d * 3 + 0] * wa0
                    + attr[(size_t)d * 3 + 1] * wa1
                    + attr[(size_t)d * 3 + 2] * wa2;
            v = silu(v);
            hs[kc2 * 512 + (r + 16 * quadp) * 8 + jp] = bf16_rne(v);
        }
    }

    v4f acc2[4];
    #pragma unroll
    for (int nt = 0; nt < 4; ++nt) acc2[nt] = (v4f){0.f, 0.f, 0.f, 0.f};

    #pragma unroll
    for (int kc = 0; kc < 2; ++kc) {
        const v8s a0 = *(const v8s*)(hs + kc * 512 + lane * 8);
        #pragma unroll
        for (int nt = 0; nt < 4; ++nt) {
            const v8s b = *(const v8s*)(W2f + ((kc * 4 + nt) * 64 + lane) * 8);
            acc2[nt] = __builtin_amdgcn_mfma_f32_16x16x32_bf16(a0, b, acc2[nt], 0, 0, 0);
        }
    }

    #pragma unroll
    for (int nt = 0; nt < 4; ++nt) {
        const int c = nt * 16 + m16;
        const float b2c = b2[c];
        #pragma unroll
        for (int reg = 0; reg < 4; ++reg) {
            const int row = quad * 4 + reg;
            hs[row * 64 + c] = bf16_rne(silu(acc2[nt][reg] + b2c));
        }
    }
    #pragma unroll
    for (int i = 0; i < 2; ++i) {
        const v8s row16 = *(const v8s*)(hs + i * 512 + lane * 8);
        *(v8s*)(h2 + (size_t)D0 * 64 + i * 512 + lane * 8) = row16;
    }
}

// ====== aggregate (tier A): j-side STREAMING + k-side gather via permk2 ======
// R10: h2j is j-sorted, so each node's j-rows are contiguous (pure stream, no
// indirection). k-rows gather h2j[permk2[e]] with R9's proven batched idiom.
// Random rows halved: 2M -> 1M.
__global__ __launch_bounds__(256, 4) void aggregate_hyb(
    const unsigned short* __restrict__ h2j,
    const int* __restrict__ off_j, const int* __restrict__ off_k,
    const int* __restrict__ permk2,
    const float* __restrict__ W34, const float* __restrict__ b34,
    float* __restrict__ out)
{
    __shared__ float a_lds[64 * 132];   // [node][0..63]=aggH, [128]=bias flag
    const int tid    = threadIdx.x;
    const int lane   = tid & 63;
    const int wv     = __builtin_amdgcn_readfirstlane(tid >> 6);  // 0..3
    const int base   = blockIdx.x * 64;
    const int half   = lane >> 5;
    const int lane31 = lane & 31;

#define JS_BATCH(B) \
    if (ej + B <= ej1) { \
        unsigned int rr[B]; \
        _Pragma("unroll") \
        for (int q = 0; q < B; ++q) \
            rr[q] = *(const unsigned int*)(h2j + (size_t)(ej + q) * 64 + lane31 * 2); \
        _Pragma("unroll") \
        for (int q = 0; q < B; ++q) { \
            const float2 f = bf2_to_f2(rr[q]); \
            axj += f.x; ayj += f.y; \
        } \
        ej += B; \
    }

#define KG_BATCH(B) \
    if (ek + B <= ek1) { \
        int dd[B]; \
        _Pragma("unroll") \
        for (int q = 0; q < B; ++q) dd[q] = permk2[ek + q]; \
        unsigned int rr[B]; \
        _Pragma("unroll") \
        for (int q = 0; q < B; ++q) \
            rr[q] = *(const unsigned int*)(h2j + (size_t)dd[q] * 64 + lane31 * 2); \
        _Pragma("unroll") \
        for (int q = 0; q < B; ++q) { \
            const float2 f = bf2_to_f2(rr[q]); \
            axk += f.x; ayk += f.y; \
        } \
        ek += B; \
    }

    // phase 1: half-wave h of wave wv aggregates nodes base + wv*16 + p*2 + h
    for (int p = 0; p < 8; ++p) {
        const int ln = wv * 16 + p * 2 + half;
        const int n  = base + ln;
        float sx = 0.f, sy = 0.f, bf = 0.f;
        if (n < N_NODES) {
            const int ej0 = off_j[n], ej1 = off_j[n + 1];
            const int ek0 = off_k[n], ek1 = off_k[n + 1];
            const int cj = ej1 - ej0, ck = ek1 - ek0;
            float axj = 0.f, ayj = 0.f, axk = 0.f, ayk = 0.f;
            int ej = ej0, ek = ek0;
            // combined main loop: 8 streamed j-rows + 8 gathered k-rows in flight
            while (ej + 8 <= ej1 && ek + 8 <= ek1) {
                int dk[8];
                #pragma unroll
                for (int q = 0; q < 8; ++q) dk[q] = permk2[ek + q];
                unsigned int rj[8], rk[8];
                #pragma unroll
                for (int q = 0; q < 8; ++q) {
                    rj[q] = *(const unsigned int*)(h2j + (size_t)(ej + q) * 64 + lane31 * 2);
                    rk[q] = *(const unsigned int*)(h2j + (size_t)dk[q] * 64 + lane31 * 2);
                }
                #pragma unroll
                for (int q = 0; q < 8; ++q) {
                    const float2 fj = bf2_to_f2(rj[q]); axj += fj.x; ayj += fj.y;
                    const float2 fk = bf2_to_f2(rk[q]); axk += fk.x; ayk += fk.y;
                }
                ej += 8; ek += 8;
            }
            // drain j tail (streaming 8/4/2/1)
            for (; ej + 8 <= ej1; ) { JS_BATCH(8) }
            JS_BATCH(4)
            JS_BATCH(2)
            JS_BATCH(1)
            // drain k tail (gather 8/4/2/1)
            for (; ek + 8 <= ek1; ) { KG_BATCH(8) }
            KG_BATCH(4)
            KG_BATCH(2)
            KG_BATCH(1)
            const float invj = 1.0f / (float)max(cj, 1);
            const float invk = 1.0f / (float)max(ck, 1);
            sx = axj * invj + axk * invk;
            sy = ayj * invj + ayk * invk;
            bf = 0.5f * ((float)(cj > 0) + (float)(ck > 0));
        }
        float2 w; w.x = sx * 0.5f; w.y = sy * 0.5f;
        *(float2*)&a_lds[ln * 132 + 2 * lane31] = w;
        if (lane31 == 0) a_lds[ln * 132 + 128] = bf;
    }
#undef JS_BATCH
#undef KG_BATCH
    __syncthreads();

    // phase 2: out[n] = aggH[n] @ W34 + bf*b34  (lane = node, W34 via scalar loads)
    const int co = wv * 32;
    const float bfv = a_lds[lane * 132 + 128];
    float acc[32];
    #pragma unroll
    for (int c = 0; c < 32; ++c) acc[c] = bfv * b34[co + c];
    const float* ap = &a_lds[lane * 132];
    #pragma unroll 2
    for (int d = 0; d < 64; d += 4) {
        const float4 av = *(const float4*)&ap[d];
        const float* w0 = &W34[(d + 0) * 128 + co];
        const float* w1 = w0 + 128;
        const float* w2 = w0 + 256;
        const float* w3 = w0 + 384;
        #pragma unroll
        for (int c = 0; c < 32; ++c)
            acc[c] += av.x * w0[c] + av.y * w1[c] + av.z * w2[c] + av.w * w3[c];
    }
    __syncthreads();
    #pragma unroll
    for (int c = 0; c < 32; c += 4)
        *(float4*)&a_lds[lane * 132 + co + c] = make_float4(acc[c], acc[c+1], acc[c+2], acc[c+3]);
    __syncthreads();
    const int q4 = lane31 << 2;
    #pragma unroll
    for (int p = 0; p < 8; ++p) {
        const int ln = wv * 16 + p * 2 + half;
        const int n  = base + ln;
        if (n < N_NODES)
            *(float4*)&out[(size_t)n * 128 + q4] = *(const float4*)&a_lds[ln * 132 + q4];
    }
}

// ====== aggregate (tier B): R9 half-wave-per-node gather + j/k interleave ======
__global__ __launch_bounds__(256, 4) void aggregate_out64(
    const unsigned short* __restrict__ h2,
    const int* __restrict__ off_j, const int* __restrict__ off_k,
    const int* __restrict__ perm_j, const int* __restrict__ perm_k,
    const float* __restrict__ W34, const float* __restrict__ b34,
    float* __restrict__ out)
{
    __shared__ float a_lds[64 * 132];   // [node][0..63]=aggH, [128]=bias flag
    const int tid    = threadIdx.x;
    const int lane   = tid & 63;
    const int wv     = __builtin_amdgcn_readfirstlane(tid >> 6);  // 0..3
    const int base   = blockIdx.x * 64;
    const int half   = lane >> 5;
    const int lane31 = lane & 31;

#define AGG_BATCH(B, permp, e, e1, ax, ay) \
    if (e + B <= e1) { \
        int dd[B]; \
        _Pragma("unroll") \
        for (int q = 0; q < B; ++q) dd[q] = permp[e + q]; \
        unsigned int rr[B]; \
        _Pragma("unroll") \
        for (int q = 0; q < B; ++q) \
            rr[q] = *(const unsigned int*)(h2 + (size_t)dd[q] * 64 + lane31 * 2); \
        _Pragma("unroll") \
        for (int q = 0; q < B; ++q) { \
            const float2 f = bf2_to_f2(rr[q]); \
            ax += f.x; ay += f.y; \
        } \
        e += B; \
    }

    for (int p = 0; p < 8; ++p) {
        const int ln = wv * 16 + p * 2 + half;
        const int n  = base + ln;
        float sx = 0.f, sy = 0.f, bf = 0.f;
        if (n < N_NODES) {
            const int ej0 = off_j[n], ej1 = off_j[n + 1];
            const int ek0 = off_k[n], ek1 = off_k[n + 1];
            const int cj = ej1 - ej0, ck = ek1 - ek0;
            float axj = 0.f, ayj = 0.f, axk = 0.f, ayk = 0.f;
            int ej = ej0, ek = ek0;
            while (ej + 8 <= ej1 && ek + 8 <= ek1) {
                int dj[8], dk[8];
                #pragma unroll
                for (int q = 0; q < 8; ++q) { dj[q] = perm_j[ej + q]; dk[q] = perm_k[ek + q]; }
                unsigned int rj[8], rk[8];
                #pragma unroll
                for (int q = 0; q < 8; ++q) {
                    rj[q] = *(const unsigned int*)(h2 + (size_t)dj[q] * 64 + lane31 * 2);
                    rk[q] = *(const unsigned int*)(h2 + (size_t)dk[q] * 64 + lane31 * 2);
                }
                #pragma unroll
                for (int q = 0; q < 8; ++q) {
                    const float2 fj = bf2_to_f2(rj[q]); axj += fj.x; ayj += fj.y;
                    const float2 fk = bf2_to_f2(rk[q]); axk += fk.x; ayk += fk.y;
                }
                ej += 8; ek += 8;
            }
            for (; ej + 8 <= ej1; ) { AGG_BATCH(8, perm_j, ej, ej1, axj, ayj) }
            AGG_BATCH(4, perm_j, ej, ej1, axj, ayj)
            AGG_BATCH(2, perm_j, ej, ej1, axj, ayj)
            AGG_BATCH(1, perm_j, ej, ej1, axj, ayj)
            for (; ek + 8 <= ek1; ) { AGG_BATCH(8, perm_k, ek, ek1, axk, ayk) }
            AGG_BATCH(4, perm_k, ek, ek1, axk, ayk)
            AGG_BATCH(2, perm_k, ek, ek1, axk, ayk)
            AGG_BATCH(1, perm_k, ek, ek1, axk, ayk)
            const float invj = 1.0f / (float)max(cj, 1);
            const float invk = 1.0f / (float)max(ck, 1);
            sx = axj * invj + axk * invk;
            sy = ayj * invj + ayk * invk;
            bf = 0.5f * ((float)(cj > 0) + (float)(ck > 0));
        }
        float2 w; w.x = sx * 0.5f; w.y = sy * 0.5f;
        *(float2*)&a_lds[ln * 132 + 2 * lane31] = w;
        if (lane31 == 0) a_lds[ln * 132 + 128] = bf;
    }
#undef AGG_BATCH
    __syncthreads();

    const int co = wv * 32;
    const float bfv = a_lds[lane * 132 + 128];
    float acc[32];
    #pragma unroll
    for (int c = 0; c < 32; ++c) acc[c] = bfv * b34[co + c];
    const float* ap = &a_lds[lane * 132];
    #pragma unroll 2
    for (int d = 0; d < 64; d += 4) {
        const float4 av = *(const float4*)&ap[d];
        const float* w0 = &W34[(d + 0) * 128 + co];
        const float* w1 = w0 + 128;
        const float* w2 = w0 + 256;
        const float* w3 = w0 + 384;
        #pragma unroll
        for (int c = 0; c < 32; ++c)
            acc[c] += av.x * w0[c] + av.y * w1[c] + av.z * w2[c] + av.w * w3[c];
    }
    __syncthreads();
    #pragma unroll
    for (int c = 0; c < 32; c += 4)
        *(float4*)&a_lds[lane * 132 + co + c] = make_float4(acc[c], acc[c+1], acc[c+2], acc[c+3]);
    __syncthreads();
    const int q4 = lane31 << 2;
    #pragma unroll
    for (int p = 0; p < 8; ++p) {
        const int ln = wv * 16 + p * 2 + half;
        const int n  = base + ln;
        if (n < N_NODES)
            *(float4*)&out[(size_t)n * 128 + q4] = *(const float4*)&a_lds[ln * 132 + q4];
    }
}

// ================= fallback (proven R3 atomic path) =================
__global__ void scale_kernel(const int* __restrict__ cnt_j, const int* __restrict__ cnt_k,
                             float* __restrict__ scale_j, float* __restrict__ scale_k) {
    int n = blockIdx.x * blockDim.x + threadIdx.x;
    if (n < N_NODES) {
        scale_j[n] = 0.5f / (float)max(cnt_j[n], 1);
        scale_k[n] = 0.5f / (float)max(cnt_k[n], 1);
    }
}

__global__ __launch_bounds__(256, 3) void mlp_mfma_atomic(
    const unsigned short* __restrict__ xb, const int* __restrict__ qidx,
    const float* __restrict__ attr,
    const float* __restrict__ W1, const float* __restrict__ b1,
    const float* __restrict__ b2, const float* __restrict__ b3,
    const unsigned short* __restrict__ W1f, const unsigned short* __restrict__ W2f,
    const unsigned short* __restrict__ W3f,
    const float* __restrict__ scale_j, const float* __restrict__ scale_k,
    float* __restrict__ aggr)
{
    __shared__ __align__(16) unsigned short hbuf[4][4096];
    const int tid  = threadIdx.x;
    const int lane = tid & 63;
    const int wv   = tid >> 6;
    const int g    = blockIdx.x * 4 + wv;
    if (g >= NWAVES) return;
    const int D0   = g * 32;
    const int m16  = lane & 15;
    const int quad = lane >> 4;
    unsigned short* hs = hbuf[wv];

    int irow[2], lrow[2];
    irow[0] = qidx[D0 + m16];
    irow[1] = qidx[D0 + 16 + m16];
    lrow[0] = qidx[3 * N_DIH + D0 + m16];
    lrow[1] = qidx[3 * N_DIH + D0 + 16 + m16];

    v4f acc[2][4];
    #pragma unroll
    for (int mt = 0; mt < 2; ++mt)
        #pragma unroll
        for (int nt = 0; nt < 4; ++nt) acc[mt][nt] = (v4f){0.f, 0.f, 0.f, 0.f};
    #pragma unroll
    for (int kc = 0; kc < 8; ++kc) {
        const int side = kc >> 2;
        const int coff = (kc & 3) * 32 + quad * 8;
        const int r0 = side ? lrow[0] : irow[0];
        const int r1 = side ? lrow[1] : irow[1];
        const v8s a0 = *(const v8s*)(xb + (size_t)r0 * 128 + coff);
        const v8s a1 = *(const v8s*)(xb + (size_t)r1 * 128 + coff);
        #pragma unroll
        for (int nt = 0; nt < 4; ++nt) {
            const v8s b = *(const v8s*)(W1f + ((kc * 4 + nt) * 64 + lane) * 8);
            acc[0][nt] = __builtin_amdgcn_mfma_f32_16x16x32_bf16(a0, b, acc[0][nt], 0, 0, 0);
            acc[1][nt] = __builtin_amdgcn_mfma_f32_16x16x32_bf16(a1, b, acc[1][nt], 0, 0, 0);
        }
    }
    #pragma unroll
    for (int mt = 0; mt < 2; ++mt) {
        #pragma unroll
        for (int nt = 0; nt < 4; ++nt) {
            const int c = nt * 16 + m16;
            const float b1c = b1[c];
            const float wa0 = W1[256 * 64 + c];
            const float wa1 = W1[257 * 64 + c];
            const float wa2 = W1[258 * 64 + c];
            const int quadp = (nt * 2 + (m16 >> 3)) & 3;
            const int jp    = m16 & 7;
            const int kc2   = nt >> 1;
            #pragma unroll
            for (int reg = 0; reg < 4; ++reg) {
                const int r = quad * 4 + reg;
                const int d = D0 + mt * 16 + r;
                float v = acc[mt][nt][reg] + b1c
                        + attr[(size_t)d * 3 + 0] * wa0
                        + attr[(size_t)d * 3 + 1] * wa1
                        + attr[(size_t)d * 3 + 2] * wa2;
                v = silu(v);
                hs[mt * 1024 + kc2 * 512 + (r + 16 * quadp) * 8 + jp] = bf16_rne(v);
            }
        }
    }
    v4f acc2[2][4];
    #pragma unroll
    for (int mt = 0; mt < 2; ++mt)
        #pragma unroll
        for (int nt = 0; nt < 4; ++nt) acc2[mt][nt] = (v4f){0.f, 0.f, 0.f, 0.f};
    #pragma unroll
    for (int kc = 0; kc < 2; ++kc) {
        const v8s a0 = *(const v8s*)(hs +        kc * 512 + lane * 8);
        const v8s a1 = *(const v8s*)(hs + 1024 + kc * 512 + lane * 8);
        #pragma unroll
        for (int nt = 0; nt < 4; ++nt) {
            const v8s b = *(const v8s*)(W2f + ((kc * 4 + nt) * 64 + lane) * 8);
            acc2[0][nt] = __builtin_amdgcn_mfma_f32_16x16x32_bf16(a0, b, acc2[0][nt], 0, 0, 0);
            acc2[1][nt] = __builtin_amdgcn_mfma_f32_16x16x32_bf16(a1, b, acc2[1][nt], 0, 0, 0);
        }
    }
    #pragma unroll
    for (int mt = 0; mt < 2; ++mt) {
        #pragma unroll
        for (int nt = 0; nt < 4; ++nt) {
            const float b2c = b2[nt * 16 + m16];
            const int quadp = (nt * 2 + (m16 >> 3)) & 3;
            const int jp    = m16 & 7;
            const int kc2   = nt >> 1;
            #pragma unroll
            for (int reg = 0; reg < 4; ++reg) {
                const int r = quad * 4 + reg;
                const float v = silu(acc2[mt][nt][reg] + b2c);
                hs[2048 + mt * 1024 + kc2 * 512 + (r + 16 * quadp) * 8 + jp] = bf16_rne(v);
            }
        }
    }
    v4f acc3[2][8];
    #pragma unroll
    for (int mt = 0; mt < 2; ++mt)
        #pragma unroll
        for (int nt = 0; nt < 8; ++nt) acc3[mt][nt] = (v4f){0.f, 0.f, 0.f, 0.f};
    #pragma unroll
    for (int kc = 0; kc < 2; ++kc) {
        const v8s a0 = *(const v8s*)(hs + 2048 +        kc * 512 + lane * 8);
        const v8s a1 = *(const v8s*)(hs + 2048 + 1024 + kc * 512 + lane * 8);
        #pragma unroll
        for (int nt = 0; nt < 8; ++nt) {
            const v8s b = *(const v8s*)(W3f + ((kc * 8 + nt) * 64 + lane) * 8);
            acc3[0][nt] = __builtin_amdgcn_mfma_f32_16x16x32_bf16(a0, b, acc3[0][nt], 0, 0, 0);
            acc3[1][nt] = __builtin_amdgcn_mfma_f32_16x16x32_bf16(a1, b, acc3[1][nt], 0, 0, 0);
        }
    }
    #pragma unroll
    for (int mt = 0; mt < 2; ++mt) {
        int jn[4], kn[4]; float sjv[4], skv[4];
        #pragma unroll
        for (int reg = 0; reg < 4; ++reg) {
            const int d = D0 + mt * 16 + quad * 4 + reg;
            jn[reg] = qidx[N_DIH + d];
            kn[reg] = qidx[2 * N_DIH + d];
            sjv[reg] = scale_j[jn[reg]];
            skv[reg] = scale_k[kn[reg]];
        }
        #pragma unroll
        for (int nt = 0; nt < 8; ++nt) {
            const int c = nt * 16 + m16;
            const float b3c = b3[c];
            #pragma unroll
            for (int reg = 0; reg < 4; ++reg) {
                const float v = acc3[mt][nt][reg] + b3c;
                atomicAdd(&aggr[(size_t)jn[reg] * 128 + c], v * sjv[reg]);
                atomicAdd(&aggr[(size_t)kn[reg] * 128 + c], v * skv[reg]);
            }
        }
    }
}

#define OB    256
#define OTILE 64
__global__ __launch_bounds__(OB, 2) void out_kernel(const float* __restrict__ aggr,
                                                    const float* __restrict__ Wout,
                                                    float* __restrict__ out) {
    __shared__ float a_lds[OTILE * 132];
    const int tid  = threadIdx.x;
    const int lane = tid & 63;
    const int wv   = __builtin_amdgcn_readfirstlane(tid >> 6);
    const int base = blockIdx.x * OTILE;
    const int half = lane >> 5;
    const int q4   = (lane & 31) << 2;
    #pragma unroll
    for (int p = 0; p < 8; ++p) {
        const int ln = wv * 16 + p * 2 + half;
        const int n  = base + ln;
        float4 v = make_float4(0.f, 0.f, 0.f, 0.f);
        if (n < N_NODES) v = *(const float4*)&aggr[(size_t)n * 128 + q4];
        *(float4*)&a_lds[ln * 132 + q4] = v;
    }
    __syncthreads();
    const int c0 = wv * 32;
    float acc[32];
    #pragma unroll
    for (int c = 0; c < 32; ++c) acc[c] = 0.0f;
    const float* ap = &a_lds[lane * 132];
    #pragma unroll 2
    for (int d = 0; d < 128; d += 4) {
        const float4 av = *(const float4*)&ap[d];
        const float* w0 = &Wout[(d + 0) * 128 + c0];
        const float* w1 = &Wout[(d + 1) * 128 + c0];
        const float* w2 = &Wout[(d + 2) * 128 + c0];
        const float* w3 = &Wout[(d + 3) * 128 + c0];
        #pragma unroll
        for (int c = 0; c < 32; ++c)
            acc[c] += av.x * w0[c] + av.y * w1[c] + av.z * w2[c] + av.w * w3[c];
    }
    __syncthreads();
    #pragma unroll
    for (int c = 0; c < 32; c += 4)
        *(float4*)&a_lds[lane * 132 + c0 + c] = make_float4(acc[c], acc[c+1], acc[c+2], acc[c+3]);
    __syncthreads();
    #pragma unroll
    for (int p = 0; p < 8; ++p) {
        const int ln = wv * 16 + p * 2 + half;
        const int n  = base + ln;
        if (n < N_NODES)
            *(float4*)&out[(size_t)n * 128 + q4] = *(const float4*)&a_lds[ln * 132 + q4];
    }
}

extern "C" void kernel_launch(void* const* d_in, const int* in_sizes, int n_in,
                              void* d_out, int out_size, void* d_ws, size_t ws_size,
                              hipStream_t stream) {
    const float* x    = (const float*)d_in[0];
    const int*   qidx = (const int*)d_in[1];
    const float* attr = (const float*)d_in[2];
    const float* W1   = (const float*)d_in[3];
    const float* b1   = (const float*)d_in[4];
    const float* W2   = (const float*)d_in[5];
    const float* b2   = (const float*)d_in[6];
    const float* W3   = (const float*)d_in[7];
    const float* b3   = (const float*)d_in[8];
    const float* Wout = (const float*)d_in[9];
    float* out = (float*)d_out;
    float* wsf = (float*)d_ws;

    const size_t words = ws_size / 4;
    if (words >= (size_t)47500000) {
        // ---- tier A: j-sorted scatter + hybrid aggregate (41.9M words, 167.5 MB) ----
        size_t o = 0;
        unsigned short* h2j = (unsigned short*)wsf;          o += 32000000;
        _Float16* uvp = (_Float16*)(wsf + o);                o += 6400000;   // f16 100Kx128
        unsigned short* W1f = (unsigned short*)(wsf + o);    o += 8192;
        unsigned short* W2f = (unsigned short*)(wsf + o);    o += 2048;
        unsigned short* W3f = (unsigned short*)(wsf + o);    o += 4096;
        unsigned short* W1g = (unsigned short*)(wsf + o);    o += 8192;
        float* W34  = wsf + o;                               o += 8192;
        float* b34  = wsf + o;                               o += 128;
        float* PK   = wsf + o;                               o += 256;
        int* cnt_j  = (int*)(wsf + o);                       o += 100000;
        int* cnt_k  = (int*)(wsf + o);                       o += 100000;
        int* off_j  = (int*)(wsf + o);                       o += 100001;
        int* off_k  = (int*)(wsf + o);                       o += 100001;
        int* rank_j = (int*)(wsf + o);                       o += 1000000;   // dedicated:
        int* rank_k = (int*)(wsf + o);                       o += 1000000;   // mlp2j reads
        int* permk2 = (int*)(wsf + o);                       o += 1000000;   // while writing h2j

        hipMemsetAsync(cnt_j, 0, (size_t)200000 * sizeof(int), stream);
        prep_kernel<<<PREP_MAIN, 256, 0, stream>>>(
            x, h2j /*xb unused*/, W1, W2, W3, b1, b3, Wout,
            W1f, W2f, W3f, W1g, W34, b34, PK, qidx, cnt_j, cnt_k, rank_j, rank_k);
        scan_kernel<<<2, 1024, 0, stream>>>(cnt_j, cnt_k, off_j, off_k);
        permute2_kernel<<<(N_DIH + 255) / 256, 256, 0, stream>>>(
            qidx, off_j, off_k, rank_j, rank_k, permk2);
        uv_kernel<<<(UVW + 3) / 4, 256, 0, stream>>>(x, W1g, uvp);
        mlp2j_kernel<<<NW16 / 4, 256, 0, stream>>>(
            uvp, qidx, attr, PK, W2f, b2, off_j, rank_j, h2j);
        aggregate_hyb<<<(N_NODES + 63) / 64, 256, 0, stream>>>(
            h2j, off_j, off_k, permk2, W34, b34, out);
    } else if (words >= (size_t)41100000) {
        // ---- tier B: round-1 path ----
        size_t o = 0;
        unsigned short* h2  = (unsigned short*)wsf;          o += 32000000;
        unsigned short* xb  = (unsigned short*)(wsf + o);    o += 6400000;
        unsigned short* W1f = (unsigned short*)(wsf + o);    o += 8192;
        unsigned short* W2f = (unsigned short*)(wsf + o);    o += 2048;
        unsigned short* W3f = (unsigned short*)(wsf + o);    o += 4096;
        float* W34  = wsf + o;                               o += 8192;
        float* b34  = wsf + o;                               o += 128;
        int* cnt_j  = (int*)(wsf + o);                       o += 100000;
        int* cnt_k  = (int*)(wsf + o);                       o += 100000;
        int* off_j  = (int*)(wsf + o);                       o += 100001;
        int* off_k  = (int*)(wsf + o);                       o += 100001;
        int* perm_j = (int*)(wsf + o);                       o += 1000000;
        int* perm_k = (int*)(wsf + o);                       o += 1000000;
        unsigned short* W1g = (unsigned short*)(wsf + o);    o += 8192;
        float* PK   = wsf + o;                               o += 256;
        int* rank_j = (int*)h2;
        int* rank_k = rank_j + N_DIH;

        hipMemsetAsync(cnt_j, 0, (size_t)200000 * sizeof(int), stream);
        prep_kernel<<<PREP_ALL, 256, 0, stream>>>(
            x, xb, W1, W2, W3, b1, b3, Wout,
            W1f, W2f, W3f, W1g, W34, b34, PK, qidx, cnt_j, cnt_k, rank_j, rank_k);
        scan_kernel<<<2, 1024, 0, stream>>>(cnt_j, cnt_k, off_j, off_k);
        permute_kernel<<<(N_DIH + 255) / 256, 256, 0, stream>>>(
            qidx, off_j, off_k, rank_j, rank_k, perm_j, perm_k);
        mlp12_kernel<<<NW16 / 4, 256, 0, stream>>>(
            xb, qidx, attr, W1, b1, b2, W1f, W2f, h2);
        aggregate_out64<<<(N_NODES + 63) / 64, 256, 0, stream>>>(
            h2, off_j, off_k, perm_j, perm_k, W34, b34, out);
    } else {
        // ---- tier C: proven atomic fallback (78.5 MB) ----
        int*   cnt_j   = (int*)wsf;
        int*   cnt_k   = cnt_j + N_NODES;
        float* scale_j = wsf + 200000;
        float* scale_k = wsf + 300000;
        float* aggr    = wsf + 400000;
        unsigned short* xb  = (unsigned short*)(wsf + 13200000);
        unsigned short* W1f = (unsigned short*)(wsf + 19600000);
        unsigned short* W2f = (unsigned short*)(wsf + 19608192);
        unsigned short* W3f = (unsigned short*)(wsf + 19610240);
        float* W34 = wsf + 19612288;   // scratch (unused result ok)
        float* b34 = wsf + 19612288;   // overlap fine for fallback
        unsigned short* W1g = (unsigned short*)(wsf + 19612288); // scratch overlap
        float* PK  = wsf + 19612288;   // scratch overlap

        hipMemsetAsync(cnt_j, 0, (size_t)2 * N_NODES * sizeof(int), stream);
        hipMemsetAsync(aggr, 0, (size_t)N_NODES * 128 * sizeof(float), stream);
        prep_kernel<<<PREP_ALL, 256, 0, stream>>>(
            x, xb, W1, W2, W3, b1, b3, Wout,
            W1f, W2f, W3f, W1g, W34, b34, PK, qidx, cnt_j, cnt_k, nullptr, nullptr);
        scale_kernel<<<(N_NODES + 255) / 256, 256, 0, stream>>>(cnt_j, cnt_k, scale_j, scale_k);
        mlp_mfma_atomic<<<(NWAVES + 3) / 4, 256, 0, stream>>>(
            xb, qidx, attr, W1, b1, b2, b3, W1f, W2f, W3f, scale_j, scale_k, aggr);
        out_kernel<<<(N_NODES + OTILE - 1) / OTILE, OB, 0, stream>>>(aggr, Wout, out);
    }
}